// Round 4
// baseline (41988.354 us; speedup 1.0000x reference)
//
#include <hip/hip_runtime.h>
#include <hip/hip_cooperative_groups.h>
#include <math.h>

namespace cg = cooperative_groups;

// ---------------- model constants ----------------
// HD=256 NL=4 NH=8 DH=32 MP=8 MS=32 T=40 ES=64 BATCH=8 BEAMS=5 BB=40
// START=1 END=2 MIN_LL_PEN=-100000
// Prefill (ti=0): beams within a batch identical -> 72 rows (8 batches x 9),
// K/V stored in batch-leader slot (b*5), ptr ancestry points at leader.

// ---------------- conv kernels (round-3, correctness-proven) ----------------
template <int IC, int OC, int OD, int CHUNKS>
__global__ __launch_bounds__(256) void conv_v1(const float* __restrict__ in,
                                               const float* __restrict__ w,
                                               const float* __restrict__ bias,
                                               float* __restrict__ out) {
  constexpr int ID = OD * 2;
  constexpr int ID2 = ID * ID;
  __shared__ float wl[IC * 64];
  int bi = blockIdx.x;
  int chunk = bi % CHUNKS;
  int oc = (bi / CHUNKS) % OC;
  int b = bi / (CHUNKS * OC);
  for (int i = threadIdx.x; i < IC * 64; i += 256) wl[i] = w[oc * IC * 64 + i];
  __syncthreads();
  int s = chunk * 256 + threadIdx.x;
  if (s >= OD * OD * OD) return;
  int od = s / (OD * OD), oh = (s / OD) % OD, ow = s % OD;
  float acc = 0.f;
  for (int ic = 0; ic < IC; ++ic) {
    const float* ipb = in + (size_t)(b * IC + ic) * (ID * ID2);
    const float* wp = wl + ic * 64;
#pragma unroll
    for (int kd = 0; kd < 4; ++kd) {
      int id = od * 2 - 1 + kd;
      if ((unsigned)id < (unsigned)ID) {
#pragma unroll
        for (int kh = 0; kh < 4; ++kh) {
          int ih = oh * 2 - 1 + kh;
          if ((unsigned)ih < (unsigned)ID) {
            const float* rowp = ipb + id * ID2 + ih * ID;
#pragma unroll
            for (int kw = 0; kw < 4; ++kw) {
              int iw = ow * 2 - 1 + kw;
              if ((unsigned)iw < (unsigned)ID)
                acc = fmaf(rowp[iw], wp[kd * 16 + kh * 4 + kw], acc);
            }
          }
        }
      }
    }
  }
  acc += bias[oc];
  out[((size_t)(b * OC + oc) * OD + od) * (OD * OD) + oh * OD + ow] = fmaxf(acc, 0.f);
}

__global__ __launch_bounds__(256) void conv_t2(const float* __restrict__ in,
                                               const float* __restrict__ w,
                                               const float* __restrict__ bias,
                                               float* __restrict__ out) {
  __shared__ float patch[2][4864];
  __shared__ float wl[2][512];
  const int bi = blockIdx.x;
  const int od = bi & 15;
  const int ocg = (bi >> 4) & 7;
  const int b = bi >> 7;
  const int t = threadIdx.x;
  const int oh = t >> 4, ow = t & 15;
  int off[19];
#pragma unroll
  for (int n = 0; n < 19; ++n) {
    int idx = t + n * 256;
    off[n] = -1;
    if (idx < 4624) {
      int kd = idx / 1156;
      int r = idx - kd * 1156;
      int py = r / 34, px = r - py * 34;
      int id = od * 2 - 1 + kd;
      int ih = py - 1, iw = px - 1;
      if ((unsigned)id < 32u && (unsigned)ih < 32u && (unsigned)iw < 32u)
        off[n] = (b * 32) * 32768 + id * 1024 + ih * 32 + iw;
    }
  }
  const int wbase = (ocg * 8 + (t >> 6)) * 32 * 64 + (t & 63);
  const int wbase2 = (ocg * 8 + ((t + 256) >> 6)) * 32 * 64 + (t & 63);
#pragma unroll
  for (int n = 0; n < 19; ++n) patch[0][t + n * 256] = (off[n] >= 0) ? in[off[n]] : 0.f;
  wl[0][t] = w[wbase];
  wl[0][t + 256] = w[wbase2];
  __syncthreads();
  float acc[8];
#pragma unroll
  for (int o = 0; o < 8; ++o) acc[o] = 0.f;
  for (int ic = 0; ic < 32; ++ic) {
    const int buf = ic & 1;
    float rv[19], wr0 = 0.f, wr1 = 0.f;
    if (ic < 31) {
#pragma unroll
      for (int n = 0; n < 19; ++n)
        rv[n] = (off[n] >= 0) ? in[off[n] + (ic + 1) * 32768] : 0.f;
      wr0 = w[wbase + (ic + 1) * 64];
      wr1 = w[wbase2 + (ic + 1) * 64];
    }
    const float* pb = &patch[buf][0];
    const float* wb = &wl[buf][0];
#pragma unroll
    for (int kd = 0; kd < 4; ++kd)
#pragma unroll
      for (int kh = 0; kh < 4; ++kh) {
        const float* prow = pb + kd * 1156 + (oh * 2 + kh) * 34 + ow * 2;
#pragma unroll
        for (int kw = 0; kw < 4; ++kw) {
          float iv = prow[kw];
          int tap = kd * 16 + kh * 4 + kw;
#pragma unroll
          for (int o = 0; o < 8; ++o) acc[o] = fmaf(iv, wb[o * 64 + tap], acc[o]);
        }
      }
    __syncthreads();
    if (ic < 31) {
#pragma unroll
      for (int n = 0; n < 19; ++n) patch[buf ^ 1][t + n * 256] = rv[n];
      wl[buf ^ 1][t] = wr0;
      wl[buf ^ 1][t + 256] = wr1;
    }
    __syncthreads();
  }
#pragma unroll
  for (int o = 0; o < 8; ++o) {
    int oc = ocg * 8 + o;
    out[(((size_t)(b * 64 + oc) * 16 + od) * 16 + oh) * 16 + ow] =
        fmaxf(acc[o] + bias[oc], 0.f);
  }
}

__global__ __launch_bounds__(256) void conv_t3(const float* __restrict__ in,
                                               const float* __restrict__ w,
                                               const float* __restrict__ bias,
                                               float* __restrict__ out) {
  __shared__ float patch[2][3328];
  __shared__ float wl[2][256];
  const int bi = blockIdx.x;
  const int ocg = bi & 31;
  const int odg = (bi >> 5) & 1;
  const int b = bi >> 6;
  const int t = threadIdx.x;
  const int od_l = t >> 6;
  const int oh = (t >> 3) & 7, ow = t & 7;
  int off[13];
#pragma unroll
  for (int n = 0; n < 13; ++n) {
    int idx = t + n * 256;
    off[n] = -1;
    if (idx < 3240) {
      int s = idx / 324;
      int r = idx - s * 324;
      int py = r / 18, px = r - py * 18;
      int id = odg * 8 - 1 + s;
      int ih = py - 1, iw = px - 1;
      if ((unsigned)id < 16u && (unsigned)ih < 16u && (unsigned)iw < 16u)
        off[n] = (b * 64) * 4096 + id * 256 + ih * 16 + iw;
    }
  }
  const int wbase = (ocg * 4 + (t >> 6)) * 64 * 64 + (t & 63);
#pragma unroll
  for (int n = 0; n < 13; ++n) patch[0][t + n * 256] = (off[n] >= 0) ? in[off[n]] : 0.f;
  wl[0][t] = w[wbase];
  __syncthreads();
  float acc[4];
#pragma unroll
  for (int o = 0; o < 4; ++o) acc[o] = 0.f;
  for (int ic = 0; ic < 64; ++ic) {
    const int buf = ic & 1;
    float rv[13], wr0 = 0.f;
    if (ic < 63) {
#pragma unroll
      for (int n = 0; n < 13; ++n)
        rv[n] = (off[n] >= 0) ? in[off[n] + (ic + 1) * 4096] : 0.f;
      wr0 = w[wbase + (ic + 1) * 64];
    }
    const float* pb = &patch[buf][0];
    const float* wb = &wl[buf][0];
#pragma unroll
    for (int kd = 0; kd < 4; ++kd) {
      int s = od_l * 2 + kd;
#pragma unroll
      for (int kh = 0; kh < 4; ++kh) {
        const float* prow = pb + s * 324 + (oh * 2 + kh) * 18 + ow * 2;
#pragma unroll
        for (int kw = 0; kw < 4; ++kw) {
          float iv = prow[kw];
          int tap = kd * 16 + kh * 4 + kw;
#pragma unroll
          for (int o = 0; o < 4; ++o) acc[o] = fmaf(iv, wb[o * 64 + tap], acc[o]);
        }
      }
    }
    __syncthreads();
    if (ic < 63) {
#pragma unroll
      for (int n = 0; n < 13; ++n) patch[buf ^ 1][t + n * 256] = rv[n];
      wl[buf ^ 1][t] = wr0;
    }
    __syncthreads();
  }
  int od = odg * 4 + od_l;
#pragma unroll
  for (int o = 0; o < 4; ++o) {
    int oc = ocg * 4 + o;
    out[(((size_t)(b * 128 + oc) * 8 + od) * 8 + oh) * 8 + ow] =
        fmaxf(acc[o] + bias[oc], 0.f);
  }
}

__global__ __launch_bounds__(64) void conv_v2(const float* __restrict__ in,
                                              const float* __restrict__ w,
                                              const float* __restrict__ bias,
                                              float* __restrict__ out) {
  constexpr int IC = 128, OD = 4, ID = 8, ID2 = 64;
  __shared__ float wl[IC * 64];
  int oc = blockIdx.x % 256;
  int b = blockIdx.x / 256;
  for (int i = threadIdx.x; i < IC * 64; i += 64) wl[i] = w[oc * IC * 64 + i];
  __syncthreads();
  int s = threadIdx.x;
  int od = s >> 4, oh = (s >> 2) & 3, ow = s & 3;
  float acc = 0.f;
  for (int ic = 0; ic < IC; ++ic) {
    const float* ipb = in + (size_t)(b * IC + ic) * (ID * ID2);
    const float* wp = wl + ic * 64;
#pragma unroll
    for (int kd = 0; kd < 4; ++kd) {
      int id = od * 2 - 1 + kd;
      if ((unsigned)id < (unsigned)ID) {
#pragma unroll
        for (int kh = 0; kh < 4; ++kh) {
          int ih = oh * 2 - 1 + kh;
          if ((unsigned)ih < (unsigned)ID) {
            const float* rowp = ipb + id * ID2 + ih * ID;
#pragma unroll
            for (int kw = 0; kw < 4; ++kw) {
              int iw = ow * 2 - 1 + kw;
              if ((unsigned)iw < (unsigned)ID)
                acc = fmaf(rowp[iw], wp[kd * 16 + kh * 4 + kw], acc);
            }
          }
        }
      }
    }
  }
  acc += bias[oc];
  out[((size_t)(b * 256 + oc) * OD + od) * 16 + oh * 4 + ow] = fmaxf(acc, 0.f);
}

__global__ __launch_bounds__(256) void conv_v3(const float* __restrict__ in,
                                               const float* __restrict__ w,
                                               const float* __restrict__ bias,
                                               float* __restrict__ codes) {
  __shared__ float inl[256 * 64];
  int b = blockIdx.x >> 3;
  int ocg = blockIdx.x & 7;
  for (int i = threadIdx.x; i < 256 * 64; i += 256) inl[i] = in[b * 256 * 64 + i];
  __syncthreads();
  int oc = ocg * 32 + (threadIdx.x >> 3);
  int s = threadIdx.x & 7;
  int od = s >> 2, oh = (s >> 1) & 1, ow = s & 1;
  const float* wp = w + (size_t)oc * 256 * 64;
  float acc = 0.f;
  for (int ic = 0; ic < 256; ++ic) {
    const float* ib = inl + ic * 64;
    const float* wb = wp + ic * 64;
#pragma unroll
    for (int kd = 0; kd < 4; ++kd) {
      int id = od * 2 - 1 + kd;
      if ((unsigned)id < 4u) {
#pragma unroll
        for (int kh = 0; kh < 4; ++kh) {
          int ih = oh * 2 - 1 + kh;
          if ((unsigned)ih < 4u) {
#pragma unroll
            for (int kw = 0; kw < 4; ++kw) {
              int iw = ow * 2 - 1 + kw;
              if ((unsigned)iw < 4u)
                acc = fmaf(ib[id * 16 + ih * 4 + iw], wb[kd * 16 + kh * 4 + kw], acc);
            }
          }
        }
      }
    }
  }
  acc += bias[oc];
  codes[(b * 8 + s) * 256 + oc] = fmaxf(acc, 0.f);
}

// ---------------- persistent cooperative decode kernel ----------------
// 256 WGs x 256 threads, 1 WG/CU. Weight slices in LDS for the whole decode.
// LDS float layout (offsets):
//   xs    [72*257]  @0       (row-major x/h2 staging, pad 257; beam arrays alias)
//   wqkv  [4*3*256] @18504   ([l][oc][k], cols = bid*3+oc of 768)
//   wff1  [4*4*256] @21576   (cols = bid*4+oc of 1024)
//   wff2  [4*1024]  @25672   (col = bid of 256)
//   ln1s/ln1b/ln2s/ln2b [1024] @29768/30792/31816/32840
//   misc  [2048]    @33864
#define SMEM_FLOATS 35912

__device__ __forceinline__ float blockSum256p(float v, float* red) {
#pragma unroll
  for (int off = 32; off >= 1; off >>= 1) v += __shfl_xor(v, off);
  __syncthreads();
  if ((threadIdx.x & 63) == 0) red[threadIdx.x >> 6] = v;
  __syncthreads();
  return red[0] + red[1] + red[2] + red[3];
}

__global__ void k_decode(
    const float* __restrict__ codes, const float* __restrict__ tok_emb,
    const float* __restrict__ pos_emb, const float* __restrict__ Wqkv,
    const float* __restrict__ Wo, const float* __restrict__ ln1s,
    const float* __restrict__ ln1b, const float* __restrict__ ln2s,
    const float* __restrict__ ln2b, const float* __restrict__ Wff1,
    const float* __restrict__ bff1, const float* __restrict__ Wff2,
    const float* __restrict__ bff2, const float* __restrict__ hW1,
    const float* __restrict__ hb1, const float* __restrict__ hW2,
    const float* __restrict__ hb2, float* __restrict__ Kc, float* __restrict__ Vc,
    float* __restrict__ q, float* __restrict__ h2, float* __restrict__ f1T,
    float* __restrict__ x, float* __restrict__ logits, int* __restrict__ bseqs,
    float* __restrict__ blls, int* __restrict__ ptr) {
  extern __shared__ float sm[];
  float* xs = sm;
  float* s_wqkv = sm + 18504;
  float* s_wff1 = sm + 21576;
  float* s_wff2 = sm + 25672;
  float* s_l1s = sm + 29768;
  float* s_l1b = sm + 30792;
  float* s_l2s = sm + 31816;
  float* s_l2b = sm + 32840;
  float* misc = sm + 33864;
  const int t = threadIdx.x;
  const int bid = blockIdx.x;
  const int lane = t & 63;
  const int wv = t >> 6;
  cg::grid_group grid = cg::this_grid();

  // ===== init: stage weight slices + LN params; build prefill x; init state =====
  for (int idx = t; idx < 3072; idx += 256) {
    int l = idx / 768, r2 = idx - l * 768;
    int oc = r2 >> 8, k = r2 & 255;
    s_wqkv[idx] = Wqkv[l * 196608 + k * 768 + bid * 3 + oc];
  }
  for (int idx = t; idx < 4096; idx += 256) {
    int l = idx >> 10, r2 = idx & 1023;
    int oc = r2 >> 8, k = r2 & 255;
    s_wff1[idx] = Wff1[l * 262144 + k * 1024 + bid * 4 + oc];
  }
  for (int idx = t; idx < 4096; idx += 256) {
    int l = idx >> 10, k = idx & 1023;
    s_wff2[idx] = Wff2[l * 262144 + k * 256 + bid];
  }
  for (int idx = t; idx < 1024; idx += 256) {
    s_l1s[idx] = ln1s[idx];
    s_l1b[idx] = ln1b[idx];
    s_l2s[idx] = ln2s[idx];
    s_l2b[idx] = ln2b[idx];
  }
  for (int idx = bid * 256 + t; idx < 72 * 256; idx += 256 * 256) {
    int i = idx >> 8, c = idx & 255;
    int b = i / 9, ri = i - b * 9;
    float v = (ri < 8) ? codes[(b * 8 + ri) * 256 + c] : tok_emb[256 + c];  // START=1
    x[idx] = v + pos_emb[ri * 256 + c];
  }
  if (bid == 1) {
    for (int j = t; j < 1280; j += 256) bseqs[j] = ((j & 31) == 0) ? 1 : 0;
    if (t < 40) blls[t] = (t % 5 == 0) ? 0.f : -100000.0f;
    for (int j = t; j < 1600; j += 256) ptr[j] = ((j / 40) / 5) * 5;  // leader
  }
  grid.sync();

  for (int ti = 0; ti < 31; ++ti) {
    const bool pre = (ti == 0);
    const int M = pre ? 72 : 40;
    const int nrch = pre ? 2 : 1;
    for (int l = 0; l < 4; ++l) {
      // ===== phase A: LN1 + QKV (col-split, LDS weights) =====
      {
        for (int idx = t; idx < M * 256; idx += 256)
          xs[(idx >> 8) * 257 + (idx & 255)] = x[idx];
        __syncthreads();
        float* s_mean = misc;
        float* s_rsd = misc + 72;
        for (int r = wv; r < M; r += 4) {
          const float* xp = &xs[r * 257];
          float s = xp[lane] + xp[lane + 64] + xp[lane + 128] + xp[lane + 192];
#pragma unroll
          for (int off = 32; off >= 1; off >>= 1) s += __shfl_xor(s, off);
          float mean = s * (1.f / 256.f);
          float d0 = xp[lane] - mean, d1 = xp[lane + 64] - mean;
          float d2 = xp[lane + 128] - mean, d3 = xp[lane + 192] - mean;
          float v = d0 * d0 + d1 * d1 + d2 * d2 + d3 * d3;
#pragma unroll
          for (int off = 32; off >= 1; off >>= 1) v += __shfl_xor(v, off);
          if (lane == 0) {
            s_mean[r] = mean;
            s_rsd[r] = 1.f / sqrtf(v * (1.f / 256.f) + 1e-5f);
          }
        }
        __syncthreads();
        for (int idx = t; idx < M * 256; idx += 256) {
          int r = idx >> 8, k = idx & 255;
          xs[r * 257 + k] = (xs[r * 257 + k] - s_mean[r]) * s_rsd[r] * s_l1s[l * 256 + k] +
                            s_l1b[l * 256 + k];
        }
        __syncthreads();
        for (int j = wv; j < 3 * nrch; j += 4) {
          int oc = j / nrch, rc = j - oc * nrch;
          int r = (rc << 6) + lane;
          if (r < M) {
            const float* wp = &s_wqkv[(l * 3 + oc) * 256];
            const float* xp = &xs[r * 257];
            float acc = 0.f;
#pragma unroll 8
            for (int k = 0; k < 256; ++k) acc = fmaf(xp[k], wp[k], acc);
            int c = bid * 3 + oc;
            int slot, row;
            if (pre) {
              int b = r / 9;
              slot = b * 5;
              row = r - b * 9;
            } else {
              slot = r;
              row = 8 + ti;
            }
            if (c < 256)
              q[r * 256 + c] = acc;
            else if (c < 512)
              Kc[((size_t)(l * 40 + slot) * 40 + row) * 256 + (c - 256)] = acc;
            else
              Vc[((size_t)(l * 40 + slot) * 40 + row) * 256 + (c - 512)] = acc;
          }
        }
      }
      grid.sync();
      // ===== phase B: attn + Wo + residual + LN2 (per-job WG) =====
      if (bid < M) {
        int slot, row;
        if (pre) {
          int b = bid / 9;
          slot = b * 5;
          row = bid - b * 9;
        } else {
          slot = bid;
          row = 8 + ti;
        }
        float* qs = misc;             // 256
        float* ao = misc + 256;       // 256
        float* ps = misc + 512;       // 320
        float* sc = misc + 832;       // 320
        float* mh = misc + 1152;      // 8
        float* sh = misc + 1160;      // 8
        float* red = misc + 1168;     // 4
        int* ips = (int*)(misc + 1172);  // 40
        if (t < 40) ips[t] = ptr[slot * 40 + t];
        qs[t] = q[bid * 256 + t];
        __syncthreads();
        for (int hj = t; hj < 320; hj += 256) {
          int h = hj / 40, j = hj - h * 40;
          if (j <= row) {
            const float* kp = Kc + ((size_t)(l * 40 + ips[j]) * 40 + j) * 256 + h * 32;
            float s = 0.f;
#pragma unroll
            for (int dd = 0; dd < 32; ++dd) s = fmaf(qs[h * 32 + dd], kp[dd], s);
            sc[h * 40 + j] = s * 0.17677669529663687f;
          }
        }
        __syncthreads();
        if (t < 8) {
          float m = -3.4e38f;
          for (int j = 0; j <= row; ++j) m = fmaxf(m, sc[t * 40 + j]);
          float s = 0.f;
          for (int j = 0; j <= row; ++j) s += expf(sc[t * 40 + j] - m);
          mh[t] = m;
          sh[t] = s;
        }
        __syncthreads();
        for (int hj = t; hj < 320; hj += 256) {
          int h = hj / 40, j = hj - h * 40;
          if (j <= row) ps[h * 40 + j] = expf(sc[h * 40 + j] - mh[h]) / sh[h];
        }
        __syncthreads();
        {
          int h = t >> 5;
          float o = 0.f;
          for (int j = 0; j <= row; ++j)
            o = fmaf(ps[h * 40 + j], Vc[((size_t)(l * 40 + ips[j]) * 40 + j) * 256 + t], o);
          ao[t] = o;
        }
        __syncthreads();
        float acc = 0.f;
        const float* wop = Wo + (size_t)l * 65536 + t;
#pragma unroll 8
        for (int k = 0; k < 256; ++k) acc = fmaf(ao[k], wop[k * 256], acc);
        float xv = x[bid * 256 + t] + acc;
        x[bid * 256 + t] = xv;
        float mean = blockSum256p(xv, red) * (1.f / 256.f);
        float dv = xv - mean;
        float var = blockSum256p(dv * dv, red) * (1.f / 256.f);
        float rsd = 1.f / sqrtf(var + 1e-5f);
        h2[bid * 256 + t] = dv * rsd * s_l2s[l * 256 + t] + s_l2b[l * 256 + t];
      }
      grid.sync();
      // ===== phase C: FF1 (col-split, LDS weights), write f1 transposed =====
      {
        for (int idx = t; idx < M * 256; idx += 256)
          xs[(idx >> 8) * 257 + (idx & 255)] = h2[idx];
        __syncthreads();
        for (int j = wv; j < 4 * nrch; j += 4) {
          int oc = j / nrch, rc = j - oc * nrch;
          int r = (rc << 6) + lane;
          if (r < M) {
            const float* wp = &s_wff1[(l * 4 + oc) * 256];
            const float* xp = &xs[r * 257];
            float acc = 0.f;
#pragma unroll 8
            for (int k = 0; k < 256; ++k) acc = fmaf(xp[k], wp[k], acc);
            int c = bid * 4 + oc;
            f1T[c * 72 + r] = fmaxf(acc + bff1[l * 1024 + c], 0.f);
          }
        }
      }
      grid.sync();
      // ===== phase D: FF2 + residual (col = bid) =====
      {
        float* pb = misc;  // 4*72
        const float* wp = &s_wff2[l * 1024 + wv * 256];
        const float* fp = f1T + (size_t)(wv * 256) * 72;
        for (int r = lane; r < M; r += 64) {
          float acc = 0.f;
#pragma unroll 8
          for (int k = 0; k < 256; ++k) acc = fmaf(fp[k * 72 + r], wp[k], acc);
          pb[wv * 72 + r] = acc;
        }
        __syncthreads();
        for (int r = t; r < M; r += 256) {
          float s = pb[r] + pb[72 + r] + pb[144 + r] + pb[216 + r];
          x[r * 256 + bid] = x[r * 256 + bid] + s + bff2[l * 256 + bid];
        }
      }
      grid.sync();
    }
    // ===== phase H: head (per-job WG, streamed hW1/hW2) =====
    {
      int NJ = pre ? 8 : 40;
      if (bid < NJ) {
        int i = pre ? (bid * 9 + 8) : bid;
        float* xr = misc;
        float* f1h = misc + 256;
        float* pb2 = misc + 512;
        xr[t] = x[i * 256 + t];
        __syncthreads();
        float a = 0.f;
        const float* w1 = hW1 + t;
#pragma unroll 8
        for (int k = 0; k < 256; ++k) a = fmaf(xr[k], w1[k * 256], a);
        f1h[t] = fmaxf(a + hb1[t], 0.f);
        __syncthreads();
        int c = t & 63, ksg = t >> 6;
        float g2 = 0.f;
        const float* w2 = hW2 + ksg * 64 * 64 + c;
#pragma unroll
        for (int k = 0; k < 64; ++k) g2 = fmaf(f1h[ksg * 64 + k], w2[k * 64], g2);
        pb2[t] = g2;
        __syncthreads();
        if (t < 64) {
          float sv = pb2[t] + pb2[64 + t] + pb2[128 + t] + pb2[192 + t] + hb2[t];
          if (pre) {
#pragma unroll
            for (int bm = 0; bm < 5; ++bm) logits[(bid * 5 + bm) * 64 + t] = sv;
          } else {
            logits[bid * 64 + t] = sv;
          }
        }
      }
    }
    grid.sync();
    // ===== phase Beam: WG0, exact tie semantics + next-x embedding =====
    if (bid == 0) {
      float* lg = xs;              // 2560
      float* bdist = xs + 2560;    // 2560
      float* rm = xs + 5120;       // 40
      float* rsum = xs + 5160;     // 40
      float* bd = xs + 5200;       // 200
      int* bc = (int*)(xs + 5400); // 200
      float* oll = xs + 5600;      // 40
      float* nll = xs + 5640;      // 40
      int* nts = (int*)(xs + 5680);   // 40
      int* oldx = (int*)(xs + 5720);  // 40
      int* oseq = (int*)(xs + 5760);  // 1280
      int* optr = (int*)(xs + 7040);  // 1600
      for (int i = t; i < 2560; i += 256) lg[i] = logits[i];
      for (int i = t; i < 1280; i += 256) oseq[i] = bseqs[i];
      for (int i = t; i < 1600; i += 256) optr[i] = ptr[i];
      if (t < 40) oll[t] = blls[t];
      __syncthreads();
      if (t < 40) {
        float m = -3.4e38f;
        for (int j = 0; j < 64; ++j) m = fmaxf(m, lg[t * 64 + j]);
        float s = 0.f;
        for (int j = 0; j < 64; ++j) s += expf(lg[t * 64 + j] - m);
        rm[t] = m;
        rsum[t] = s;
      }
      __syncthreads();
      for (int i = t; i < 2560; i += 256) {
        int r = i >> 6, j = i & 63;
        bdist[i] = logf(expf(lg[i] - rm[r]) / rsum[r] + 1e-8f);
      }
      __syncthreads();
      if (t < 40) {
        float pv = 3.4e38f;
        int pi = -1;
        for (int r = 0; r < 5; ++r) {
          float bv = -3.4e38f;
          int bi = -1;
          for (int j = 0; j < 64; ++j) {
            float v = bdist[t * 64 + j];
            bool lessprev = (v < pv) || (v == pv && j > pi);
            if (lessprev && v > bv) { bv = v; bi = j; }
          }
          bd[t * 5 + r] = bv;
          bc[t * 5 + r] = bi;
          pv = bv;
          pi = bi;
        }
      }
      __syncthreads();
      if (t < 8) {
        float pv = 3.4e38f;
        int pi = -1;
        for (int r = 0; r < 5; ++r) {
          float bv = -3.4e38f;
          int bi = -1;
          for (int idx = 0; idx < 25; ++idx) {
            int kb = idx / 5, j = idx % 5;
            float v = bd[(t * 5 + kb) * 5 + j] + oll[t * 5 + kb];
            bool lessprev = (v < pv) || (v == pv && idx > pi);
            if (lessprev && v > bv) { bv = v; bi = idx; }
          }
          int kb = bi / 5, j = bi % 5;
          int tok = bc[(t * 5 + kb) * 5 + j];
          int bbn = t * 5 + r;
          nts[bbn] = tok;
          oldx[bbn] = t * 5 + kb;
          nll[bbn] = (tok == 2) ? (bv - 100000.0f) : bv;
          pv = bv;
          pi = bi;
        }
      }
      __syncthreads();
      for (int i = t; i < 1280; i += 256) {
        int bb = i >> 5, j = i & 31;
        int v = oseq[oldx[bb] * 32 + j];
        if (j == ti + 1) v = nts[bb];
        bseqs[i] = v;
      }
      int r1 = 8 + ti;
      for (int i = t; i < 1600; i += 256) {
        int bb = i / 40, j = i - bb * 40;
        ptr[i] = (j <= r1) ? optr[oldx[bb] * 40 + j] : bb;
      }
      if (t < 40) blls[t] = nll[t];
      const float* pe = pos_emb + (9 + ti) * 256;
      for (int i = t; i < 40 * 256; i += 256) {
        int bb = i >> 8, c = i & 255;
        x[i] = tok_emb[nts[bb] * 256 + c] + pe[c];
      }
    }
    grid.sync();
  }
}

// ---------------- final output ----------------
__global__ void k_out(const int* __restrict__ bseqs, const float* __restrict__ blls,
                      float* __restrict__ out) {
  int t = blockIdx.x * 256 + threadIdx.x;
  if (t < 1280) out[t] = (float)bseqs[t];
  else if (t < 1320) out[t] = blls[t - 1280];
}

// ---------------- host ----------------
extern "C" void kernel_launch(void* const* d_in, const int* in_sizes, int n_in,
                              void* d_out, int out_size, void* d_ws, size_t ws_size,
                              hipStream_t stream) {
  const float* voxels = (const float*)d_in[0];
  const float* ck1 = (const float*)d_in[1];
  const float* cb1 = (const float*)d_in[2];
  const float* ck2 = (const float*)d_in[3];
  const float* cb2 = (const float*)d_in[4];
  const float* ck3 = (const float*)d_in[5];
  const float* cb3 = (const float*)d_in[6];
  const float* ck4 = (const float*)d_in[7];
  const float* cb4 = (const float*)d_in[8];
  const float* ck5 = (const float*)d_in[9];
  const float* cb5 = (const float*)d_in[10];
  const float* tok_emb = (const float*)d_in[11];
  const float* pos_emb = (const float*)d_in[12];
  const float* Wqkv = (const float*)d_in[13];
  const float* Wo = (const float*)d_in[14];
  const float* ln1s = (const float*)d_in[15];
  const float* ln1b = (const float*)d_in[16];
  const float* ln2s = (const float*)d_in[17];
  const float* ln2b = (const float*)d_in[18];
  const float* Wff1 = (const float*)d_in[19];
  const float* bff1 = (const float*)d_in[20];
  const float* Wff2 = (const float*)d_in[21];
  const float* bff2 = (const float*)d_in[22];
  const float* hW1 = (const float*)d_in[23];
  const float* hb1 = (const float*)d_in[24];
  const float* hW2 = (const float*)d_in[25];
  const float* hb2 = (const float*)d_in[26];

  float* ws = (float*)d_ws;
  // conv chain buffers
  float* c1 = ws;              // 8,388,608 f
  float* c2 = c1 + 8388608;    // 2,097,152 f
  float* c3 = c2 + 2097152;    //   524,288 f
  float* c4 = c3 + 524288;     //   131,072 f
  float* codes = c4 + 131072;  //    16,384 f  (offset 11,141,120)
  // decode region aliases c1 (dead after conv_t2)
  float* Kc = ws;                  // 1,638,400 f
  float* Vc = Kc + 1638400;        // 1,638,400 f
  float* qb = Vc + 1638400;        // 18,432 f
  float* h2 = qb + 18432;          // 18,432 f
  float* f1T = h2 + 18432;         // 73,728 f (1024 x 72)
  float* xb = f1T + 73728;         // 18,432 f
  float* logits = xb + 18432;      // 2,560 f
  float* blls = logits + 2560;     // 40 f
  int* bseqs = (int*)(blls + 40);  // 1,280 i
  int* ptr = bseqs + 1280;         // 1,600 i

  conv_v1<1, 32, 32, 128><<<8 * 32 * 128, 256, 0, stream>>>(voxels, ck1, cb1, c1);
  conv_t2<<<8 * 16 * 8, 256, 0, stream>>>(c1, ck2, cb2, c2);
  conv_t3<<<8 * 2 * 32, 256, 0, stream>>>(c2, ck3, cb3, c3);
  conv_v2<<<8 * 256, 64, 0, stream>>>(c3, ck4, cb4, c4);
  conv_v3<<<8 * 8, 256, 0, stream>>>(c4, ck5, cb5, codes);

  static bool attr_set = false;
  if (!attr_set) {
    hipFuncSetAttribute((const void*)k_decode,
                        hipFuncAttributeMaxDynamicSharedMemorySize,
                        SMEM_FLOATS * 4);
    attr_set = true;
  }
  void* args[] = {(void*)&codes, (void*)&tok_emb, (void*)&pos_emb, (void*)&Wqkv,
                  (void*)&Wo,    (void*)&ln1s,    (void*)&ln1b,    (void*)&ln2s,
                  (void*)&ln2b,  (void*)&Wff1,    (void*)&bff1,    (void*)&Wff2,
                  (void*)&bff2,  (void*)&hW1,     (void*)&hb1,     (void*)&hW2,
                  (void*)&hb2,   (void*)&Kc,      (void*)&Vc,      (void*)&qb,
                  (void*)&h2,    (void*)&f1T,     (void*)&xb,      (void*)&logits,
                  (void*)&bseqs, (void*)&blls,    (void*)&ptr};
  hipLaunchCooperativeKernel((const void*)k_decode, dim3(256), dim3(256), args,
                             SMEM_FLOATS * 4, stream);

  k_out<<<6, 256, 0, stream>>>(bseqs, blls, (float*)d_out);
}

// Round 5
// 26042.084 us; speedup vs baseline: 1.6123x; 1.6123x over previous
//
#include <hip/hip_runtime.h>
#include <math.h>

// ---------------- model constants ----------------
// HD=256 NL=4 NH=8 DH=32 MP=8 MS=32 T=40 ES=64 BATCH=8 BEAMS=5 BB=40
// START=1 END=2 MIN_LL_PEN=-100000
// Decode: ONE WG per batch (8 WGs x 1024 thr), persistent over all 31 steps.
// All sync is __syncthreads(). Beam search is batch-local => no cross-WG deps.

#define FMA4(ACC, HK, W)                      \
  {                                           \
    (ACC).x = fmaf((HK), (W).x, (ACC).x);     \
    (ACC).y = fmaf((HK), (W).y, (ACC).y);     \
    (ACC).z = fmaf((HK), (W).z, (ACC).z);     \
    (ACC).w = fmaf((HK), (W).w, (ACC).w);     \
  }

// ---------------- conv kernels (proven rounds 3/4) ----------------
template <int IC, int OC, int OD, int CHUNKS>
__global__ __launch_bounds__(256) void conv_v1(const float* __restrict__ in,
                                               const float* __restrict__ w,
                                               const float* __restrict__ bias,
                                               float* __restrict__ out) {
  constexpr int ID = OD * 2;
  constexpr int ID2 = ID * ID;
  __shared__ float wl[IC * 64];
  int bi = blockIdx.x;
  int chunk = bi % CHUNKS;
  int oc = (bi / CHUNKS) % OC;
  int b = bi / (CHUNKS * OC);
  for (int i = threadIdx.x; i < IC * 64; i += 256) wl[i] = w[oc * IC * 64 + i];
  __syncthreads();
  int s = chunk * 256 + threadIdx.x;
  if (s >= OD * OD * OD) return;
  int od = s / (OD * OD), oh = (s / OD) % OD, ow = s % OD;
  float acc = 0.f;
  for (int ic = 0; ic < IC; ++ic) {
    const float* ipb = in + (size_t)(b * IC + ic) * (ID * ID2);
    const float* wp = wl + ic * 64;
#pragma unroll
    for (int kd = 0; kd < 4; ++kd) {
      int id = od * 2 - 1 + kd;
      if ((unsigned)id < (unsigned)ID) {
#pragma unroll
        for (int kh = 0; kh < 4; ++kh) {
          int ih = oh * 2 - 1 + kh;
          if ((unsigned)ih < (unsigned)ID) {
            const float* rowp = ipb + id * ID2 + ih * ID;
#pragma unroll
            for (int kw = 0; kw < 4; ++kw) {
              int iw = ow * 2 - 1 + kw;
              if ((unsigned)iw < (unsigned)ID)
                acc = fmaf(rowp[iw], wp[kd * 16 + kh * 4 + kw], acc);
            }
          }
        }
      }
    }
  }
  acc += bias[oc];
  out[((size_t)(b * OC + oc) * OD + od) * (OD * OD) + oh * OD + ow] = fmaxf(acc, 0.f);
}

__global__ __launch_bounds__(256) void conv_t2(const float* __restrict__ in,
                                               const float* __restrict__ w,
                                               const float* __restrict__ bias,
                                               float* __restrict__ out) {
  __shared__ float patch[2][4864];
  __shared__ float wl[2][512];
  const int bi = blockIdx.x;
  const int od = bi & 15;
  const int ocg = (bi >> 4) & 7;
  const int b = bi >> 7;
  const int t = threadIdx.x;
  const int oh = t >> 4, ow = t & 15;
  int off[19];
#pragma unroll
  for (int n = 0; n < 19; ++n) {
    int idx = t + n * 256;
    off[n] = -1;
    if (idx < 4624) {
      int kd = idx / 1156;
      int r = idx - kd * 1156;
      int py = r / 34, px = r - py * 34;
      int id = od * 2 - 1 + kd;
      int ih = py - 1, iw = px - 1;
      if ((unsigned)id < 32u && (unsigned)ih < 32u && (unsigned)iw < 32u)
        off[n] = (b * 32) * 32768 + id * 1024 + ih * 32 + iw;
    }
  }
  const int wbase = (ocg * 8 + (t >> 6)) * 32 * 64 + (t & 63);
  const int wbase2 = (ocg * 8 + ((t + 256) >> 6)) * 32 * 64 + (t & 63);
#pragma unroll
  for (int n = 0; n < 19; ++n) patch[0][t + n * 256] = (off[n] >= 0) ? in[off[n]] : 0.f;
  wl[0][t] = w[wbase];
  wl[0][t + 256] = w[wbase2];
  __syncthreads();
  float acc[8];
#pragma unroll
  for (int o = 0; o < 8; ++o) acc[o] = 0.f;
  for (int ic = 0; ic < 32; ++ic) {
    const int buf = ic & 1;
    float rv[19], wr0 = 0.f, wr1 = 0.f;
    if (ic < 31) {
#pragma unroll
      for (int n = 0; n < 19; ++n)
        rv[n] = (off[n] >= 0) ? in[off[n] + (ic + 1) * 32768] : 0.f;
      wr0 = w[wbase + (ic + 1) * 64];
      wr1 = w[wbase2 + (ic + 1) * 64];
    }
    const float* pb = &patch[buf][0];
    const float* wb = &wl[buf][0];
#pragma unroll
    for (int kd = 0; kd < 4; ++kd)
#pragma unroll
      for (int kh = 0; kh < 4; ++kh) {
        const float* prow = pb + kd * 1156 + (oh * 2 + kh) * 34 + ow * 2;
#pragma unroll
        for (int kw = 0; kw < 4; ++kw) {
          float iv = prow[kw];
          int tap = kd * 16 + kh * 4 + kw;
#pragma unroll
          for (int o = 0; o < 8; ++o) acc[o] = fmaf(iv, wb[o * 64 + tap], acc[o]);
        }
      }
    __syncthreads();
    if (ic < 31) {
#pragma unroll
      for (int n = 0; n < 19; ++n) patch[buf ^ 1][t + n * 256] = rv[n];
      wl[buf ^ 1][t] = wr0;
      wl[buf ^ 1][t + 256] = wr1;
    }
    __syncthreads();
  }
#pragma unroll
  for (int o = 0; o < 8; ++o) {
    int oc = ocg * 8 + o;
    out[(((size_t)(b * 64 + oc) * 16 + od) * 16 + oh) * 16 + ow] =
        fmaxf(acc[o] + bias[oc], 0.f);
  }
}

__global__ __launch_bounds__(256) void conv_t3(const float* __restrict__ in,
                                               const float* __restrict__ w,
                                               const float* __restrict__ bias,
                                               float* __restrict__ out) {
  __shared__ float patch[2][3328];
  __shared__ float wl[2][256];
  const int bi = blockIdx.x;
  const int ocg = bi & 31;
  const int odg = (bi >> 5) & 1;
  const int b = bi >> 6;
  const int t = threadIdx.x;
  const int od_l = t >> 6;
  const int oh = (t >> 3) & 7, ow = t & 7;
  int off[13];
#pragma unroll
  for (int n = 0; n < 13; ++n) {
    int idx = t + n * 256;
    off[n] = -1;
    if (idx < 3240) {
      int s = idx / 324;
      int r = idx - s * 324;
      int py = r / 18, px = r - py * 18;
      int id = odg * 8 - 1 + s;
      int ih = py - 1, iw = px - 1;
      if ((unsigned)id < 16u && (unsigned)ih < 16u && (unsigned)iw < 16u)
        off[n] = (b * 64) * 4096 + id * 256 + ih * 16 + iw;
    }
  }
  const int wbase = (ocg * 4 + (t >> 6)) * 64 * 64 + (t & 63);
#pragma unroll
  for (int n = 0; n < 13; ++n) patch[0][t + n * 256] = (off[n] >= 0) ? in[off[n]] : 0.f;
  wl[0][t] = w[wbase];
  __syncthreads();
  float acc[4];
#pragma unroll
  for (int o = 0; o < 4; ++o) acc[o] = 0.f;
  for (int ic = 0; ic < 64; ++ic) {
    const int buf = ic & 1;
    float rv[13], wr0 = 0.f;
    if (ic < 63) {
#pragma unroll
      for (int n = 0; n < 13; ++n)
        rv[n] = (off[n] >= 0) ? in[off[n] + (ic + 1) * 4096] : 0.f;
      wr0 = w[wbase + (ic + 1) * 64];
    }
    const float* pb = &patch[buf][0];
    const float* wb = &wl[buf][0];
#pragma unroll
    for (int kd = 0; kd < 4; ++kd) {
      int s = od_l * 2 + kd;
#pragma unroll
      for (int kh = 0; kh < 4; ++kh) {
        const float* prow = pb + s * 324 + (oh * 2 + kh) * 18 + ow * 2;
#pragma unroll
        for (int kw = 0; kw < 4; ++kw) {
          float iv = prow[kw];
          int tap = kd * 16 + kh * 4 + kw;
#pragma unroll
          for (int o = 0; o < 4; ++o) acc[o] = fmaf(iv, wb[o * 64 + tap], acc[o]);
        }
      }
    }
    __syncthreads();
    if (ic < 63) {
#pragma unroll
      for (int n = 0; n < 13; ++n) patch[buf ^ 1][t + n * 256] = rv[n];
      wl[buf ^ 1][t] = wr0;
    }
    __syncthreads();
  }
  int od = odg * 4 + od_l;
#pragma unroll
  for (int o = 0; o < 4; ++o) {
    int oc = ocg * 4 + o;
    out[(((size_t)(b * 128 + oc) * 8 + od) * 8 + oh) * 8 + ow] =
        fmaxf(acc[o] + bias[oc], 0.f);
  }
}

__global__ __launch_bounds__(64) void conv_v2(const float* __restrict__ in,
                                              const float* __restrict__ w,
                                              const float* __restrict__ bias,
                                              float* __restrict__ out) {
  constexpr int IC = 128, OD = 4, ID = 8, ID2 = 64;
  __shared__ float wl[IC * 64];
  int oc = blockIdx.x % 256;
  int b = blockIdx.x / 256;
  for (int i = threadIdx.x; i < IC * 64; i += 64) wl[i] = w[oc * IC * 64 + i];
  __syncthreads();
  int s = threadIdx.x;
  int od = s >> 4, oh = (s >> 2) & 3, ow = s & 3;
  float acc = 0.f;
  for (int ic = 0; ic < IC; ++ic) {
    const float* ipb = in + (size_t)(b * IC + ic) * (ID * ID2);
    const float* wp = wl + ic * 64;
#pragma unroll
    for (int kd = 0; kd < 4; ++kd) {
      int id = od * 2 - 1 + kd;
      if ((unsigned)id < (unsigned)ID) {
#pragma unroll
        for (int kh = 0; kh < 4; ++kh) {
          int ih = oh * 2 - 1 + kh;
          if ((unsigned)ih < (unsigned)ID) {
            const float* rowp = ipb + id * ID2 + ih * ID;
#pragma unroll
            for (int kw = 0; kw < 4; ++kw) {
              int iw = ow * 2 - 1 + kw;
              if ((unsigned)iw < (unsigned)ID)
                acc = fmaf(rowp[iw], wp[kd * 16 + kh * 4 + kw], acc);
            }
          }
        }
      }
    }
  }
  acc += bias[oc];
  out[((size_t)(b * 256 + oc) * OD + od) * 16 + oh * 4 + ow] = fmaxf(acc, 0.f);
}

__global__ __launch_bounds__(256) void conv_v3(const float* __restrict__ in,
                                               const float* __restrict__ w,
                                               const float* __restrict__ bias,
                                               float* __restrict__ codes) {
  __shared__ float inl[256 * 64];
  int b = blockIdx.x >> 3;
  int ocg = blockIdx.x & 7;
  for (int i = threadIdx.x; i < 256 * 64; i += 256) inl[i] = in[b * 256 * 64 + i];
  __syncthreads();
  int oc = ocg * 32 + (threadIdx.x >> 3);
  int s = threadIdx.x & 7;
  int od = s >> 2, oh = (s >> 1) & 1, ow = s & 1;
  const float* wp = w + (size_t)oc * 256 * 64;
  float acc = 0.f;
  for (int ic = 0; ic < 256; ++ic) {
    const float* ib = inl + ic * 64;
    const float* wb = wp + ic * 64;
#pragma unroll
    for (int kd = 0; kd < 4; ++kd) {
      int id = od * 2 - 1 + kd;
      if ((unsigned)id < 4u) {
#pragma unroll
        for (int kh = 0; kh < 4; ++kh) {
          int ih = oh * 2 - 1 + kh;
          if ((unsigned)ih < 4u) {
#pragma unroll
            for (int kw = 0; kw < 4; ++kw) {
              int iw = ow * 2 - 1 + kw;
              if ((unsigned)iw < 4u)
                acc = fmaf(ib[id * 16 + ih * 4 + iw], wb[kd * 16 + kh * 4 + kw], acc);
            }
          }
        }
      }
    }
  }
  acc += bias[oc];
  codes[(b * 8 + s) * 256 + oc] = fmaxf(acc, 0.f);
}

// ---------------- fused per-batch decode ----------------
// One chunk of NJ (<=5) rows through all 4 layers. PRE=1: prefill rows
// row0..row0+NJ-1 at leader slot b*5. PRE=0: NJ=5 beams, row 8+ti, own slots.
template <int PRE, int NJ>
__device__ void chunk_run(int b, int ti, int row0, const float* __restrict__ codes,
                          const float* __restrict__ tok_emb,
                          const float* __restrict__ pos_emb,
                          const float* __restrict__ Wqkv, const float* __restrict__ Wo,
                          const float* __restrict__ ln1s, const float* __restrict__ ln1b,
                          const float* __restrict__ ln2s, const float* __restrict__ ln2b,
                          const float* __restrict__ Wff1, const float* __restrict__ bff1,
                          const float* __restrict__ Wff2, const float* __restrict__ bff2,
                          float* __restrict__ Kc, float* __restrict__ Vc,
                          float (*sX)[256], float (*sH)[256], float (*sQ)[256],
                          float (*sF1)[1024], float* sP, int (*sSeq)[32],
                          int (*sPtr)[40]) {
  const int t = threadIdx.x;
  const int lane = t & 63;
  const int wv = t >> 6;
  // ---- embedding ----
  for (int i = t; i < NJ * 256; i += 1024) {
    int j = i >> 8, c = i & 255;
    int row = PRE ? (row0 + j) : (8 + ti);
    float v;
    if (PRE)
      v = (row < 8) ? codes[(b * 8 + row) * 256 + c] : tok_emb[256 + c];  // START=1
    else
      v = tok_emb[sSeq[j][ti] * 256 + c];
    sX[j][c] = v + pos_emb[row * 256 + c];
  }
  __syncthreads();

  for (int l = 0; l < 4; ++l) {
    // ---- LN1 (wave per row) ----
    if (wv < NJ) {
      float4 xv = *(const float4*)&sX[wv][lane * 4];
      float s = xv.x + xv.y + xv.z + xv.w;
#pragma unroll
      for (int off = 32; off >= 1; off >>= 1) s += __shfl_xor(s, off);
      float mean = s * (1.f / 256.f);
      float d0 = xv.x - mean, d1 = xv.y - mean, d2 = xv.z - mean, d3 = xv.w - mean;
      float v = d0 * d0 + d1 * d1 + d2 * d2 + d3 * d3;
#pragma unroll
      for (int off = 32; off >= 1; off >>= 1) v += __shfl_xor(v, off);
      float rsd = 1.f / sqrtf(v * (1.f / 256.f) + 1e-5f);
      float4 sc4 = *(const float4*)&ln1s[l * 256 + lane * 4];
      float4 bi4 = *(const float4*)&ln1b[l * 256 + lane * 4];
      float4 hv;
      hv.x = d0 * rsd * sc4.x + bi4.x;
      hv.y = d1 * rsd * sc4.y + bi4.y;
      hv.z = d2 * rsd * sc4.z + bi4.z;
      hv.w = d3 * rsd * sc4.w + bi4.w;
      *(float4*)&sH[wv][lane * 4] = hv;
    }
    __syncthreads();
    // ---- QKV: 192 threads, 4 cols each, k=256 ----
    if (t < 192) {
      float4 acc[NJ];
#pragma unroll
      for (int j = 0; j < NJ; ++j) acc[j] = make_float4(0.f, 0.f, 0.f, 0.f);
      const float* wp = Wqkv + (size_t)l * 196608 + 4 * t;
      for (int k4 = 0; k4 < 64; ++k4) {
        float4 w0 = *(const float4*)(wp + (k4 * 4 + 0) * 768);
        float4 w1 = *(const float4*)(wp + (k4 * 4 + 1) * 768);
        float4 w2 = *(const float4*)(wp + (k4 * 4 + 2) * 768);
        float4 w3 = *(const float4*)(wp + (k4 * 4 + 3) * 768);
#pragma unroll
        for (int j = 0; j < NJ; ++j) {
          float4 h4 = *(const float4*)&sH[j][k4 * 4];
          FMA4(acc[j], h4.x, w0);
          FMA4(acc[j], h4.y, w1);
          FMA4(acc[j], h4.z, w2);
          FMA4(acc[j], h4.w, w3);
        }
      }
      int c0 = 4 * t;
#pragma unroll
      for (int j = 0; j < NJ; ++j) {
        int row = PRE ? (row0 + j) : (8 + ti);
        int slot = PRE ? (b * 5) : (b * 5 + j);
        if (c0 < 256)
          *(float4*)&sQ[j][c0] = acc[j];
        else if (c0 < 512)
          *(float4*)&Kc[((size_t)(l * 40 + slot) * 40 + row) * 256 + (c0 - 256)] = acc[j];
        else
          *(float4*)&Vc[((size_t)(l * 40 + slot) * 40 + row) * 256 + (c0 - 512)] = acc[j];
      }
    }
    __syncthreads();
    // ---- attention scores ----
    for (int job = t; job < NJ * 320; job += 1024) {
      int j = job / 320, r2 = job - j * 320;
      int h = r2 / 40, jj = r2 - h * 40;
      int rowj = PRE ? (row0 + j) : (8 + ti);
      if (jj <= rowj) {
        int bm = PRE ? 0 : j;
        int slot = sPtr[bm][jj];
        const float* kp = Kc + ((size_t)(l * 40 + slot) * 40 + jj) * 256 + h * 32;
        float s = 0.f;
#pragma unroll
        for (int d4 = 0; d4 < 8; ++d4) {
          float4 kv = *(const float4*)(kp + d4 * 4);
          float4 qv = *(const float4*)&sQ[j][h * 32 + d4 * 4];
          s = fmaf(qv.x, kv.x, fmaf(qv.y, kv.y, fmaf(qv.z, kv.z, fmaf(qv.w, kv.w, s))));
        }
        sP[(j * 8 + h) * 40 + jj] = s * 0.17677669529663687f;  // 1/sqrt(32)
      }
    }
    __syncthreads();
    // ---- softmax per (row, head), in place ----
    if (t < NJ * 8) {
      int j = t >> 3, h = t & 7;
      int rowj = PRE ? (row0 + j) : (8 + ti);
      float* sc = &sP[(j * 8 + h) * 40];
      float m = -3.4e38f;
      for (int jj = 0; jj <= rowj; ++jj) m = fmaxf(m, sc[jj]);
      float sum = 0.f;
      for (int jj = 0; jj <= rowj; ++jj) sum += expf(sc[jj] - m);
      for (int jj = 0; jj <= rowj; ++jj) sc[jj] = expf(sc[jj] - m) / sum;
    }
    __syncthreads();
    // ---- PV (writes attn-out into sQ; q dead) ----
    for (int job = t; job < NJ * 256; job += 1024) {
      int j = job >> 8, c = job & 255;
      int h = c >> 5;
      int rowj = PRE ? (row0 + j) : (8 + ti);
      int bm = PRE ? 0 : j;
      const float* pp = &sP[(j * 8 + h) * 40];
      float o = 0.f;
      for (int jj = 0; jj <= rowj; ++jj) {
        int slot = sPtr[bm][jj];
        o = fmaf(pp[jj], Vc[((size_t)(l * 40 + slot) * 40 + jj) * 256 + c], o);
      }
      sQ[j][c] = o;
    }
    __syncthreads();
    // ---- Wo: 128 threads (64 quads x 2 kslices) ----
    if (t < 128) {
      int qd = t & 63, ks = t >> 6;
      float4 acc[NJ];
#pragma unroll
      for (int j = 0; j < NJ; ++j) acc[j] = make_float4(0.f, 0.f, 0.f, 0.f);
      const float* wp = Wo + (size_t)l * 65536 + 4 * qd;
      for (int k4 = ks * 32; k4 < ks * 32 + 32; ++k4) {
        float4 w0 = *(const float4*)(wp + (k4 * 4 + 0) * 256);
        float4 w1 = *(const float4*)(wp + (k4 * 4 + 1) * 256);
        float4 w2 = *(const float4*)(wp + (k4 * 4 + 2) * 256);
        float4 w3 = *(const float4*)(wp + (k4 * 4 + 3) * 256);
#pragma unroll
        for (int j = 0; j < NJ; ++j) {
          float4 h4 = *(const float4*)&sQ[j][k4 * 4];
          FMA4(acc[j], h4.x, w0);
          FMA4(acc[j], h4.y, w1);
          FMA4(acc[j], h4.z, w2);
          FMA4(acc[j], h4.w, w3);
        }
      }
#pragma unroll
      for (int j = 0; j < NJ; ++j) *(float4*)&sP[(ks * 5 + j) * 256 + 4 * qd] = acc[j];
    }
    __syncthreads();
    // ---- Wo reduce + residual + LN2 (wave per row) ----
    if (wv < NJ) {
      float4 p0 = *(const float4*)&sP[(0 * 5 + wv) * 256 + lane * 4];
      float4 p1 = *(const float4*)&sP[(1 * 5 + wv) * 256 + lane * 4];
      float4 xo = *(const float4*)&sX[wv][lane * 4];
      float4 xn;
      xn.x = xo.x + p0.x + p1.x;
      xn.y = xo.y + p0.y + p1.y;
      xn.z = xo.z + p0.z + p1.z;
      xn.w = xo.w + p0.w + p1.w;
      float s = xn.x + xn.y + xn.z + xn.w;
#pragma unroll
      for (int off = 32; off >= 1; off >>= 1) s += __shfl_xor(s, off);
      float mean = s * (1.f / 256.f);
      float d0 = xn.x - mean, d1 = xn.y - mean, d2 = xn.z - mean, d3 = xn.w - mean;
      float v = d0 * d0 + d1 * d1 + d2 * d2 + d3 * d3;
#pragma unroll
      for (int off = 32; off >= 1; off >>= 1) v += __shfl_xor(v, off);
      float rsd = 1.f / sqrtf(v * (1.f / 256.f) + 1e-5f);
      *(float4*)&sX[wv][lane * 4] = xn;
      float4 sc4 = *(const float4*)&ln2s[l * 256 + lane * 4];
      float4 bi4 = *(const float4*)&ln2b[l * 256 + lane * 4];
      float4 hv;
      hv.x = d0 * rsd * sc4.x + bi4.x;
      hv.y = d1 * rsd * sc4.y + bi4.y;
      hv.z = d2 * rsd * sc4.z + bi4.z;
      hv.w = d3 * rsd * sc4.w + bi4.w;
      *(float4*)&sH[wv][lane * 4] = hv;
    }
    __syncthreads();
    // ---- FF1: 256 threads, 4 cols each of 1024, k=256 ----
    if (t < 256) {
      float4 acc[NJ];
#pragma unroll
      for (int j = 0; j < NJ; ++j) acc[j] = make_float4(0.f, 0.f, 0.f, 0.f);
      const float* wp = Wff1 + (size_t)l * 262144 + 4 * t;
      for (int k4 = 0; k4 < 64; ++k4) {
        float4 w0 = *(const float4*)(wp + (k4 * 4 + 0) * 1024);
        float4 w1 = *(const float4*)(wp + (k4 * 4 + 1) * 1024);
        float4 w2 = *(const float4*)(wp + (k4 * 4 + 2) * 1024);
        float4 w3 = *(const float4*)(wp + (k4 * 4 + 3) * 1024);
#pragma unroll
        for (int j = 0; j < NJ; ++j) {
          float4 h4 = *(const float4*)&sH[j][k4 * 4];
          FMA4(acc[j], h4.x, w0);
          FMA4(acc[j], h4.y, w1);
          FMA4(acc[j], h4.z, w2);
          FMA4(acc[j], h4.w, w3);
        }
      }
      float4 bv = *(const float4*)&bff1[l * 1024 + 4 * t];
#pragma unroll
      for (int j = 0; j < NJ; ++j) {
        float4 r;
        r.x = fmaxf(acc[j].x + bv.x, 0.f);
        r.y = fmaxf(acc[j].y + bv.y, 0.f);
        r.z = fmaxf(acc[j].z + bv.z, 0.f);
        r.w = fmaxf(acc[j].w + bv.w, 0.f);
        *(float4*)&sF1[j][4 * t] = r;
      }
    }
    __syncthreads();
    // ---- FF2: 256 threads (64 quads x 4 kslices), k=1024 ----
    if (t < 256) {
      int qd = t & 63, ks = t >> 6;
      float4 acc[NJ];
#pragma unroll
      for (int j = 0; j < NJ; ++j) acc[j] = make_float4(0.f, 0.f, 0.f, 0.f);
      const float* wp = Wff2 + (size_t)l * 262144 + 4 * qd;
      for (int k4 = ks * 64; k4 < ks * 64 + 64; ++k4) {
        float4 w0 = *(const float4*)(wp + (k4 * 4 + 0) * 256);
        float4 w1 = *(const float4*)(wp + (k4 * 4 + 1) * 256);
        float4 w2 = *(const float4*)(wp + (k4 * 4 + 2) * 256);
        float4 w3 = *(const float4*)(wp + (k4 * 4 + 3) * 256);
#pragma unroll
        for (int j = 0; j < NJ; ++j) {
          float4 h4 = *(const float4*)&sF1[j][k4 * 4];
          FMA4(acc[j], h4.x, w0);
          FMA4(acc[j], h4.y, w1);
          FMA4(acc[j], h4.z, w2);
          FMA4(acc[j], h4.w, w3);
        }
      }
#pragma unroll
      for (int j = 0; j < NJ; ++j) *(float4*)&sP[(ks * 5 + j) * 256 + 4 * qd] = acc[j];
    }
    __syncthreads();
    // ---- FF2 reduce + residual ----
    for (int job = t; job < NJ * 256; job += 1024) {
      int j = job >> 8, c = job & 255;
      sX[j][c] += sP[(0 * 5 + j) * 256 + c] + sP[(1 * 5 + j) * 256 + c] +
                  sP[(2 * 5 + j) * 256 + c] + sP[(3 * 5 + j) * 256 + c] +
                  bff2[l * 256 + c];
    }
    __syncthreads();
  }
}

__global__ __launch_bounds__(1024) void k_fused(
    const float* __restrict__ codes, const float* __restrict__ tok_emb,
    const float* __restrict__ pos_emb, const float* __restrict__ Wqkv,
    const float* __restrict__ Wo, const float* __restrict__ ln1s,
    const float* __restrict__ ln1b, const float* __restrict__ ln2s,
    const float* __restrict__ ln2b, const float* __restrict__ Wff1,
    const float* __restrict__ bff1, const float* __restrict__ Wff2,
    const float* __restrict__ bff2, const float* __restrict__ hW1,
    const float* __restrict__ hb1, const float* __restrict__ hW2,
    const float* __restrict__ hb2, float* __restrict__ Kc, float* __restrict__ Vc,
    float* __restrict__ out) {
  __shared__ __align__(16) float sX[5][256];
  __shared__ __align__(16) float sH[5][256];
  __shared__ __align__(16) float sQ[5][256];
  __shared__ __align__(16) float sF1[5][1024];
  __shared__ __align__(16) float sP[5120];
  __shared__ __align__(16) float sLg[5][64];
  __shared__ int sSeq[5][32];
  __shared__ int sPtr[5][40];
  __shared__ float sLls[5];
  __shared__ float sMisc[160];
  __shared__ int sMiscI[64];
  const int t = threadIdx.x;
  const int b = blockIdx.x;

  // ---- init per-batch state ----
  for (int i = t; i < 160; i += 1024) sSeq[i >> 5][i & 31] = ((i & 31) == 0) ? 1 : 0;
  for (int i = t; i < 200; i += 1024) sPtr[i / 40][i % 40] = b * 5;  // leader
  if (t < 5) sLls[t] = (t == 0) ? 0.f : -100000.0f;
  __syncthreads();

  for (int ti = 0; ti < 31; ++ti) {
    const bool pre = (ti == 0);
    if (pre) {
      chunk_run<1, 5>(b, ti, 0, codes, tok_emb, pos_emb, Wqkv, Wo, ln1s, ln1b, ln2s,
                      ln2b, Wff1, bff1, Wff2, bff2, Kc, Vc, sX, sH, sQ, sF1, sP, sSeq,
                      sPtr);
      chunk_run<1, 4>(b, ti, 5, codes, tok_emb, pos_emb, Wqkv, Wo, ln1s, ln1b, ln2s,
                      ln2b, Wff1, bff1, Wff2, bff2, Kc, Vc, sX, sH, sQ, sF1, sP, sSeq,
                      sPtr);
    } else {
      chunk_run<0, 5>(b, ti, 0, codes, tok_emb, pos_emb, Wqkv, Wo, ln1s, ln1b, ln2s,
                      ln2b, Wff1, bff1, Wff2, bff2, Kc, Vc, sX, sH, sQ, sF1, sP, sSeq,
                      sPtr);
    }
    // ---- head ----
    {
      const int NJH = pre ? 1 : 5;
      // h1 = relu(x @ hW1 + hb1) -> sH
      if (t < NJH * 64) {
        int j = t >> 6, qd = t & 63;
        int src = pre ? 3 : j;  // prefill chunk B: row 8 = local 3
        float4 acc = make_float4(0.f, 0.f, 0.f, 0.f);
        const float* wp = hW1 + 4 * qd;
        for (int k4 = 0; k4 < 64; ++k4) {
          float4 w0 = *(const float4*)(wp + (k4 * 4 + 0) * 256);
          float4 w1 = *(const float4*)(wp + (k4 * 4 + 1) * 256);
          float4 w2 = *(const float4*)(wp + (k4 * 4 + 2) * 256);
          float4 w3 = *(const float4*)(wp + (k4 * 4 + 3) * 256);
          float4 h4 = *(const float4*)&sX[src][k4 * 4];
          FMA4(acc, h4.x, w0);
          FMA4(acc, h4.y, w1);
          FMA4(acc, h4.z, w2);
          FMA4(acc, h4.w, w3);
        }
        float4 bv = *(const float4*)&hb1[4 * qd];
        float4 r;
        r.x = fmaxf(acc.x + bv.x, 0.f);
        r.y = fmaxf(acc.y + bv.y, 0.f);
        r.z = fmaxf(acc.z + bv.z, 0.f);
        r.w = fmaxf(acc.w + bv.w, 0.f);
        *(float4*)&sH[j][4 * qd] = r;
      }
      __syncthreads();
      // logits = h1 @ hW2 + hb2 -> sLg
      if (t < NJH * 64) {
        int j = t >> 6, c = t & 63;
        float acc = 0.f;
        const float* wp = hW2 + c;
#pragma unroll 8
        for (int k = 0; k < 256; ++k) acc = fmaf(sH[j][k], wp[k * 64], acc);
        sLg[j][c] = acc + hb2[c];
      }
      __syncthreads();
      if (pre) {
        for (int i = t; i < 320; i += 1024) {
          int j = i >> 6, c = i & 63;
          if (j > 0) sLg[j][c] = sLg[0][c];
        }
        __syncthreads();
      }
    }
    // ---- beam update (exact tie semantics, batch-local) ----
    {
      float* bdist = &sF1[0][0];              // 320 floats
      int* osq = (int*)&sF1[1][0];            // 160 ints
      int* optr = (int*)&sF1[2][0];           // 200 ints
      float* rm = &sMisc[0];                  // 5
      float* rsum = &sMisc[8];                // 5
      float* bd = &sMisc[16];                 // 25
      float* nll = &sMisc[48];                // 5
      int* bc = &sMiscI[0];                   // 25
      int* nts = &sMiscI[32];                 // 5
      int* oldx = &sMiscI[40];                // 5
      for (int i = t; i < 160; i += 1024) osq[i] = sSeq[i >> 5][i & 31];
      for (int i = t; i < 200; i += 1024) optr[i] = sPtr[i / 40][i % 40];
      __syncthreads();
      if (t < 5) {
        float m = -3.4e38f;
        for (int j = 0; j < 64; ++j) m = fmaxf(m, sLg[t][j]);
        float s = 0.f;
        for (int j = 0; j < 64; ++j) s += expf(sLg[t][j] - m);
        rm[t] = m;
        rsum[t] = s;
      }
      __syncthreads();
      for (int i = t; i < 320; i += 1024) {
        int r = i >> 6, j = i & 63;
        bdist[i] = logf(expf(sLg[r][j] - rm[r]) / rsum[r] + 1e-8f);
      }
      __syncthreads();
      if (t < 5) {
        float pv = 3.4e38f;
        int pi = -1;
        for (int r = 0; r < 5; ++r) {
          float bv = -3.4e38f;
          int bi = -1;
          for (int j = 0; j < 64; ++j) {
            float v = bdist[t * 64 + j];
            bool lessprev = (v < pv) || (v == pv && j > pi);
            if (lessprev && v > bv) { bv = v; bi = j; }
          }
          bd[t * 5 + r] = bv;
          bc[t * 5 + r] = bi;
          pv = bv;
          pi = bi;
        }
      }
      __syncthreads();
      if (t == 0) {
        float pv = 3.4e38f;
        int pi = -1;
        for (int r = 0; r < 5; ++r) {
          float bv = -3.4e38f;
          int bi = -1;
          for (int idx = 0; idx < 25; ++idx) {
            int kb = idx / 5, jj = idx % 5;
            float v = bd[kb * 5 + jj] + sLls[kb];
            bool lessprev = (v < pv) || (v == pv && idx > pi);
            if (lessprev && v > bv) { bv = v; bi = idx; }
          }
          int kb = bi / 5, jj = bi % 5;
          int tok = bc[kb * 5 + jj];
          nts[r] = tok;
          oldx[r] = kb;
          nll[r] = (tok == 2) ? (bv - 100000.0f) : bv;
          pv = bv;
          pi = bi;
        }
      }
      __syncthreads();
      for (int i = t; i < 160; i += 1024) {
        int bm = i >> 5, j = i & 31;
        int v = osq[oldx[bm] * 32 + j];
        if (j == ti + 1) v = nts[bm];
        sSeq[bm][j] = v;
      }
      int r1 = 8 + ti;
      for (int i = t; i < 200; i += 1024) {
        int bm = i / 40, j = i % 40;
        sPtr[bm][j] = (j <= r1) ? optr[oldx[bm] * 40 + j] : (b * 5 + bm);
      }
      if (t < 5) sLls[t] = nll[t];
      __syncthreads();
    }
  }
  // ---- write output: bseqs (40,32) as float, then blls (40,) ----
  for (int i = t; i < 160; i += 1024) out[b * 160 + i] = (float)sSeq[i >> 5][i & 31];
  if (t < 5) out[1280 + b * 5 + t] = sLls[t];
}

// ---------------- host ----------------
extern "C" void kernel_launch(void* const* d_in, const int* in_sizes, int n_in,
                              void* d_out, int out_size, void* d_ws, size_t ws_size,
                              hipStream_t stream) {
  const float* voxels = (const float*)d_in[0];
  const float* ck1 = (const float*)d_in[1];
  const float* cb1 = (const float*)d_in[2];
  const float* ck2 = (const float*)d_in[3];
  const float* cb2 = (const float*)d_in[4];
  const float* ck3 = (const float*)d_in[5];
  const float* cb3 = (const float*)d_in[6];
  const float* ck4 = (const float*)d_in[7];
  const float* cb4 = (const float*)d_in[8];
  const float* ck5 = (const float*)d_in[9];
  const float* cb5 = (const float*)d_in[10];
  const float* tok_emb = (const float*)d_in[11];
  const float* pos_emb = (const float*)d_in[12];
  const float* Wqkv = (const float*)d_in[13];
  const float* Wo = (const float*)d_in[14];
  const float* ln1s = (const float*)d_in[15];
  const float* ln1b = (const float*)d_in[16];
  const float* ln2s = (const float*)d_in[17];
  const float* ln2b = (const float*)d_in[18];
  const float* Wff1 = (const float*)d_in[19];
  const float* bff1 = (const float*)d_in[20];
  const float* Wff2 = (const float*)d_in[21];
  const float* bff2 = (const float*)d_in[22];
  const float* hW1 = (const float*)d_in[23];
  const float* hb1 = (const float*)d_in[24];
  const float* hW2 = (const float*)d_in[25];
  const float* hb2 = (const float*)d_in[26];

  float* ws = (float*)d_ws;
  // conv chain buffers
  float* c1 = ws;              // 8,388,608 f
  float* c2 = c1 + 8388608;    // 2,097,152 f
  float* c3 = c2 + 2097152;    //   524,288 f
  float* c4 = c3 + 524288;     //   131,072 f
  float* codes = c4 + 131072;  //    16,384 f
  // decode K/V caches alias c1 (dead after conv_t2)
  float* Kc = ws;            // 1,638,400 f
  float* Vc = Kc + 1638400;  // 1,638,400 f

  conv_v1<1, 32, 32, 128><<<8 * 32 * 128, 256, 0, stream>>>(voxels, ck1, cb1, c1);
  conv_t2<<<8 * 16 * 8, 256, 0, stream>>>(c1, ck2, cb2, c2);
  conv_t3<<<8 * 2 * 32, 256, 0, stream>>>(c2, ck3, cb3, c3);
  conv_v2<<<8 * 256, 64, 0, stream>>>(c3, ck4, cb4, c4);
  conv_v3<<<8 * 8, 256, 0, stream>>>(c4, ck5, cb5, codes);

  k_fused<<<8, 1024, 0, stream>>>(codes, tok_emb, pos_emb, Wqkv, Wo, ln1s, ln1b, ln2s,
                                  ln2b, Wff1, bff1, Wff2, bff2, hW1, hb1, hW2, hb2, Kc,
                                  Vc, (float*)d_out);
}

// Round 6
// 17830.392 us; speedup vs baseline: 2.3549x; 1.4605x over previous
//
#include <hip/hip_runtime.h>
#include <math.h>

// ---------------- model constants ----------------
// HD=256 NL=4 NH=8 DH=32 MP=8 MS=32 T=40 ES=64 BATCH=8 BEAMS=5 BB=40
// START=1 END=2 MIN_LL_PEN=-100000
// Decode: 8 groups (one per batch) x 8 WGs x 512 thr. Each WG owns a column
// slice of every GEMM; cross-WG data via global + custom memory-side barrier.

#define FMA4(ACC, HK, W)                  \
  {                                       \
    (ACC).x = fmaf((HK), (W).x, (ACC).x); \
    (ACC).y = fmaf((HK), (W).y, (ACC).y); \
    (ACC).z = fmaf((HK), (W).z, (ACC).z); \
    (ACC).w = fmaf((HK), (W).w, (ACC).w); \
  }

// ---------------- conv kernels (proven rounds 3-5, unchanged) ----------------
template <int IC, int OC, int OD, int CHUNKS>
__global__ __launch_bounds__(256) void conv_v1(const float* __restrict__ in,
                                               const float* __restrict__ w,
                                               const float* __restrict__ bias,
                                               float* __restrict__ out) {
  constexpr int ID = OD * 2;
  constexpr int ID2 = ID * ID;
  __shared__ float wl[IC * 64];
  int bi = blockIdx.x;
  int chunk = bi % CHUNKS;
  int oc = (bi / CHUNKS) % OC;
  int b = bi / (CHUNKS * OC);
  for (int i = threadIdx.x; i < IC * 64; i += 256) wl[i] = w[oc * IC * 64 + i];
  __syncthreads();
  int s = chunk * 256 + threadIdx.x;
  if (s >= OD * OD * OD) return;
  int od = s / (OD * OD), oh = (s / OD) % OD, ow = s % OD;
  float acc = 0.f;
  for (int ic = 0; ic < IC; ++ic) {
    const float* ipb = in + (size_t)(b * IC + ic) * (ID * ID2);
    const float* wp = wl + ic * 64;
#pragma unroll
    for (int kd = 0; kd < 4; ++kd) {
      int id = od * 2 - 1 + kd;
      if ((unsigned)id < (unsigned)ID) {
#pragma unroll
        for (int kh = 0; kh < 4; ++kh) {
          int ih = oh * 2 - 1 + kh;
          if ((unsigned)ih < (unsigned)ID) {
            const float* rowp = ipb + id * ID2 + ih * ID;
#pragma unroll
            for (int kw = 0; kw < 4; ++kw) {
              int iw = ow * 2 - 1 + kw;
              if ((unsigned)iw < (unsigned)ID)
                acc = fmaf(rowp[iw], wp[kd * 16 + kh * 4 + kw], acc);
            }
          }
        }
      }
    }
  }
  acc += bias[oc];
  out[((size_t)(b * OC + oc) * OD + od) * (OD * OD) + oh * OD + ow] = fmaxf(acc, 0.f);
}

__global__ __launch_bounds__(256) void conv_t2(const float* __restrict__ in,
                                               const float* __restrict__ w,
                                               const float* __restrict__ bias,
                                               float* __restrict__ out) {
  __shared__ float patch[2][4864];
  __shared__ float wl[2][512];
  const int bi = blockIdx.x;
  const int od = bi & 15;
  const int ocg = (bi >> 4) & 7;
  const int b = bi >> 7;
  const int t = threadIdx.x;
  const int oh = t >> 4, ow = t & 15;
  int off[19];
#pragma unroll
  for (int n = 0; n < 19; ++n) {
    int idx = t + n * 256;
    off[n] = -1;
    if (idx < 4624) {
      int kd = idx / 1156;
      int r = idx - kd * 1156;
      int py = r / 34, px = r - py * 34;
      int id = od * 2 - 1 + kd;
      int ih = py - 1, iw = px - 1;
      if ((unsigned)id < 32u && (unsigned)ih < 32u && (unsigned)iw < 32u)
        off[n] = (b * 32) * 32768 + id * 1024 + ih * 32 + iw;
    }
  }
  const int wbase = (ocg * 8 + (t >> 6)) * 32 * 64 + (t & 63);
  const int wbase2 = (ocg * 8 + ((t + 256) >> 6)) * 32 * 64 + (t & 63);
#pragma unroll
  for (int n = 0; n < 19; ++n) patch[0][t + n * 256] = (off[n] >= 0) ? in[off[n]] : 0.f;
  wl[0][t] = w[wbase];
  wl[0][t + 256] = w[wbase2];
  __syncthreads();
  float acc[8];
#pragma unroll
  for (int o = 0; o < 8; ++o) acc[o] = 0.f;
  for (int ic = 0; ic < 32; ++ic) {
    const int buf = ic & 1;
    float rv[19], wr0 = 0.f, wr1 = 0.f;
    if (ic < 31) {
#pragma unroll
      for (int n = 0; n < 19; ++n)
        rv[n] = (off[n] >= 0) ? in[off[n] + (ic + 1) * 32768] : 0.f;
      wr0 = w[wbase + (ic + 1) * 64];
      wr1 = w[wbase2 + (ic + 1) * 64];
    }
    const float* pb = &patch[buf][0];
    const float* wb = &wl[buf][0];
#pragma unroll
    for (int kd = 0; kd < 4; ++kd)
#pragma unroll
      for (int kh = 0; kh < 4; ++kh) {
        const float* prow = pb + kd * 1156 + (oh * 2 + kh) * 34 + ow * 2;
#pragma unroll
        for (int kw = 0; kw < 4; ++kw) {
          float iv = prow[kw];
          int tap = kd * 16 + kh * 4 + kw;
#pragma unroll
          for (int o = 0; o < 8; ++o) acc[o] = fmaf(iv, wb[o * 64 + tap], acc[o]);
        }
      }
    __syncthreads();
    if (ic < 31) {
#pragma unroll
      for (int n = 0; n < 19; ++n) patch[buf ^ 1][t + n * 256] = rv[n];
      wl[buf ^ 1][t] = wr0;
      wl[buf ^ 1][t + 256] = wr1;
    }
    __syncthreads();
  }
#pragma unroll
  for (int o = 0; o < 8; ++o) {
    int oc = ocg * 8 + o;
    out[(((size_t)(b * 64 + oc) * 16 + od) * 16 + oh) * 16 + ow] =
        fmaxf(acc[o] + bias[oc], 0.f);
  }
}

__global__ __launch_bounds__(256) void conv_t3(const float* __restrict__ in,
                                               const float* __restrict__ w,
                                               const float* __restrict__ bias,
                                               float* __restrict__ out) {
  __shared__ float patch[2][3328];
  __shared__ float wl[2][256];
  const int bi = blockIdx.x;
  const int ocg = bi & 31;
  const int odg = (bi >> 5) & 1;
  const int b = bi >> 6;
  const int t = threadIdx.x;
  const int od_l = t >> 6;
  const int oh = (t >> 3) & 7, ow = t & 7;
  int off[13];
#pragma unroll
  for (int n = 0; n < 13; ++n) {
    int idx = t + n * 256;
    off[n] = -1;
    if (idx < 3240) {
      int s = idx / 324;
      int r = idx - s * 324;
      int py = r / 18, px = r - py * 18;
      int id = odg * 8 - 1 + s;
      int ih = py - 1, iw = px - 1;
      if ((unsigned)id < 16u && (unsigned)ih < 16u && (unsigned)iw < 16u)
        off[n] = (b * 64) * 4096 + id * 256 + ih * 16 + iw;
    }
  }
  const int wbase = (ocg * 4 + (t >> 6)) * 64 * 64 + (t & 63);
#pragma unroll
  for (int n = 0; n < 13; ++n) patch[0][t + n * 256] = (off[n] >= 0) ? in[off[n]] : 0.f;
  wl[0][t] = w[wbase];
  __syncthreads();
  float acc[4];
#pragma unroll
  for (int o = 0; o < 4; ++o) acc[o] = 0.f;
  for (int ic = 0; ic < 64; ++ic) {
    const int buf = ic & 1;
    float rv[13], wr0 = 0.f;
    if (ic < 63) {
#pragma unroll
      for (int n = 0; n < 13; ++n)
        rv[n] = (off[n] >= 0) ? in[off[n] + (ic + 1) * 4096] : 0.f;
      wr0 = w[wbase + (ic + 1) * 64];
    }
    const float* pb = &patch[buf][0];
    const float* wb = &wl[buf][0];
#pragma unroll
    for (int kd = 0; kd < 4; ++kd) {
      int s = od_l * 2 + kd;
#pragma unroll
      for (int kh = 0; kh < 4; ++kh) {
        const float* prow = pb + s * 324 + (oh * 2 + kh) * 18 + ow * 2;
#pragma unroll
        for (int kw = 0; kw < 4; ++kw) {
          float iv = prow[kw];
          int tap = kd * 16 + kh * 4 + kw;
#pragma unroll
          for (int o = 0; o < 4; ++o) acc[o] = fmaf(iv, wb[o * 64 + tap], acc[o]);
        }
      }
    }
    __syncthreads();
    if (ic < 63) {
#pragma unroll
      for (int n = 0; n < 13; ++n) patch[buf ^ 1][t + n * 256] = rv[n];
      wl[buf ^ 1][t] = wr0;
    }
    __syncthreads();
  }
  int od = odg * 4 + od_l;
#pragma unroll
  for (int o = 0; o < 4; ++o) {
    int oc = ocg * 4 + o;
    out[(((size_t)(b * 128 + oc) * 8 + od) * 8 + oh) * 8 + ow] =
        fmaxf(acc[o] + bias[oc], 0.f);
  }
}

__global__ __launch_bounds__(64) void conv_v2(const float* __restrict__ in,
                                              const float* __restrict__ w,
                                              const float* __restrict__ bias,
                                              float* __restrict__ out) {
  constexpr int IC = 128, OD = 4, ID = 8, ID2 = 64;
  __shared__ float wl[IC * 64];
  int oc = blockIdx.x % 256;
  int b = blockIdx.x / 256;
  for (int i = threadIdx.x; i < IC * 64; i += 64) wl[i] = w[oc * IC * 64 + i];
  __syncthreads();
  int s = threadIdx.x;
  int od = s >> 4, oh = (s >> 2) & 3, ow = s & 3;
  float acc = 0.f;
  for (int ic = 0; ic < IC; ++ic) {
    const float* ipb = in + (size_t)(b * IC + ic) * (ID * ID2);
    const float* wp = wl + ic * 64;
#pragma unroll
    for (int kd = 0; kd < 4; ++kd) {
      int id = od * 2 - 1 + kd;
      if ((unsigned)id < (unsigned)ID) {
#pragma unroll
        for (int kh = 0; kh < 4; ++kh) {
          int ih = oh * 2 - 1 + kh;
          if ((unsigned)ih < (unsigned)ID) {
            const float* rowp = ipb + id * ID2 + ih * ID;
#pragma unroll
            for (int kw = 0; kw < 4; ++kw) {
              int iw = ow * 2 - 1 + kw;
              if ((unsigned)iw < (unsigned)ID)
                acc = fmaf(rowp[iw], wp[kd * 16 + kh * 4 + kw], acc);
            }
          }
        }
      }
    }
  }
  acc += bias[oc];
  out[((size_t)(b * 256 + oc) * OD + od) * 16 + oh * 4 + ow] = fmaxf(acc, 0.f);
}

__global__ __launch_bounds__(256) void conv_v3(const float* __restrict__ in,
                                               const float* __restrict__ w,
                                               const float* __restrict__ bias,
                                               float* __restrict__ codes) {
  __shared__ float inl[256 * 64];
  int b = blockIdx.x >> 3;
  int ocg = blockIdx.x & 7;
  for (int i = threadIdx.x; i < 256 * 64; i += 256) inl[i] = in[b * 256 * 64 + i];
  __syncthreads();
  int oc = ocg * 32 + (threadIdx.x >> 3);
  int s = threadIdx.x & 7;
  int od = s >> 2, oh = (s >> 1) & 1, ow = s & 1;
  const float* wp = w + (size_t)oc * 256 * 64;
  float acc = 0.f;
  for (int ic = 0; ic < 256; ++ic) {
    const float* ib = inl + ic * 64;
    const float* wb = wp + ic * 64;
#pragma unroll
    for (int kd = 0; kd < 4; ++kd) {
      int id = od * 2 - 1 + kd;
      if ((unsigned)id < 4u) {
#pragma unroll
        for (int kh = 0; kh < 4; ++kh) {
          int ih = oh * 2 - 1 + kh;
          if ((unsigned)ih < 4u) {
#pragma unroll
            for (int kw = 0; kw < 4; ++kw) {
              int iw = ow * 2 - 1 + kw;
              if ((unsigned)iw < 4u)
                acc = fmaf(ib[id * 16 + ih * 4 + iw], wb[kd * 16 + kh * 4 + kw], acc);
            }
          }
        }
      }
    }
  }
  acc += bias[oc];
  codes[(b * 8 + s) * 256 + oc] = fmaxf(acc, 0.f);
}

// ---------------- 8-WG group barrier (memory-side, agent scope) ----------------
__device__ __forceinline__ void gbar(int* bar, int e) {
  __syncthreads();
  if (threadIdx.x == 0) {
    __threadfence();  // release: write back dirty L2 (agent scope)
    int prev = __hip_atomic_fetch_add(&bar[0], 1, __ATOMIC_ACQ_REL, __HIP_MEMORY_SCOPE_AGENT);
    if (prev == 7) {
      __hip_atomic_store(&bar[0], 0, __ATOMIC_RELAXED, __HIP_MEMORY_SCOPE_AGENT);
      __hip_atomic_fetch_add(&bar[16], 1, __ATOMIC_RELEASE, __HIP_MEMORY_SCOPE_AGENT);
    } else {
      while (__hip_atomic_load(&bar[16], __ATOMIC_ACQUIRE, __HIP_MEMORY_SCOPE_AGENT) < e)
        __builtin_amdgcn_s_sleep(2);
    }
    __threadfence();  // acquire: invalidate L1/L2 before reading peers' data
  }
  __syncthreads();
}

// ---------------- GEMM column-slice helpers ----------------
// partials: part[((qd*KS+ks)*5 + j)*4 + c]
template <int NQ, int KS, int KCH, int NJ>
__device__ __forceinline__ void slice_gemm(const float* __restrict__ W, int ldw,
                                           int cbase, const float* __restrict__ act,
                                           int actstride, float* __restrict__ part) {
  const int t = threadIdx.x;
  if (t < NQ * KS) {
    int qd = t % NQ, ks = t / NQ;
    float4 acc[NJ];
#pragma unroll
    for (int j = 0; j < NJ; ++j) acc[j] = make_float4(0.f, 0.f, 0.f, 0.f);
    const float* wp = W + (size_t)(ks * KCH) * ldw + cbase + qd * 4;
    const float* ap = act + ks * KCH;
#pragma unroll
    for (int kk = 0; kk < KCH; ++kk) {
      float4 w4 = *(const float4*)(wp + (size_t)kk * ldw);
#pragma unroll
      for (int j = 0; j < NJ; ++j) FMA4(acc[j], ap[j * actstride + kk], w4);
    }
#pragma unroll
    for (int j = 0; j < NJ; ++j) *(float4*)&part[((qd * KS + ks) * 5 + j) * 4] = acc[j];
  }
}

template <int NQ, int KS, int NJ, typename F>
__device__ __forceinline__ void slice_reduce(const float* __restrict__ part, F&& emit) {
  for (int i = threadIdx.x; i < NQ * NJ * 4; i += 512) {
    int qd = i / (NJ * 4), r = i % (NJ * 4), j = r >> 2, c = r & 3;
    float s = 0.f;
#pragma unroll
    for (int ks = 0; ks < KS; ++ks) s += part[((qd * KS + ks) * 5 + j) * 4 + c];
    emit(qd * 4 + c, j, s);
  }
}

__device__ __forceinline__ void ln_rows(const float (*sxx)[256], float (*shh)[256],
                                        const float* __restrict__ gsc,
                                        const float* __restrict__ gbi, int NJ) {
  int wv = threadIdx.x >> 6, lane = threadIdx.x & 63;
  if (wv < NJ) {
    float4 xv = *(const float4*)&sxx[wv][lane * 4];
    float s = xv.x + xv.y + xv.z + xv.w;
#pragma unroll
    for (int off = 32; off >= 1; off >>= 1) s += __shfl_xor(s, off);
    float mean = s * (1.f / 256.f);
    float d0 = xv.x - mean, d1 = xv.y - mean, d2 = xv.z - mean, d3 = xv.w - mean;
    float v = d0 * d0 + d1 * d1 + d2 * d2 + d3 * d3;
#pragma unroll
    for (int off = 32; off >= 1; off >>= 1) v += __shfl_xor(v, off);
    float rsd = 1.f / sqrtf(v * (1.f / 256.f) + 1e-5f);
    float4 s4 = *(const float4*)&gsc[lane * 4];
    float4 b4 = *(const float4*)&gbi[lane * 4];
    float4 hv;
    hv.x = d0 * rsd * s4.x + b4.x;
    hv.y = d1 * rsd * s4.y + b4.y;
    hv.z = d2 * rsd * s4.z + b4.z;
    hv.w = d3 * rsd * s4.w + b4.w;
    *(float4*)&shh[wv][lane * 4] = hv;
  }
}

// ---------------- per-chunk transformer layers ----------------
template <int PRE, int NJ>
__device__ void run_chunk(int b, int w, int ti, int rbase, const float* __restrict__ codes,
                          const float* __restrict__ tok_emb,
                          const float* __restrict__ pos_emb,
                          const float* __restrict__ Wqkv, const float* __restrict__ Wo,
                          const float* __restrict__ ln1s, const float* __restrict__ ln1b,
                          const float* __restrict__ ln2s, const float* __restrict__ ln2b,
                          const float* __restrict__ Wff1, const float* __restrict__ bff1,
                          const float* __restrict__ Wff2, const float* __restrict__ bff2,
                          float* __restrict__ Kc, float* __restrict__ Vc,
                          float* __restrict__ shq, float* __restrict__ shxn,
                          float* __restrict__ shxf, float* __restrict__ shf1,
                          const int* __restrict__ shseq, const int* __restrict__ shptr,
                          float (*sx)[256], float (*sh)[256], float* arena,
                          int (*ips)[40], int* bar, int& eb) {
  const int t = threadIdx.x;
  // ---- embedding (redundant per WG, block-local) ----
  for (int i = t; i < NJ * 256; i += 512) {
    int j = i >> 8, c = i & 255;
    int row = PRE ? (rbase + j) : (8 + ti);
    float v;
    if (PRE)
      v = (row < 8) ? codes[(b * 8 + row) * 256 + c] : tok_emb[256 + c];  // START=1
    else {
      int tok = shseq[b * 160 + j * 32 + ti];
      v = tok_emb[tok * 256 + c];
    }
    sx[j][c] = v + pos_emb[row * 256 + c];
  }
  __syncthreads();

  for (int l = 0; l < 4; ++l) {
    // ---- LN1 -> sh ----
    ln_rows(sx, sh, ln1s + l * 256, ln1b + l * 256, NJ);
    __syncthreads();
    // ---- QKV slice (cols w*96..w*96+95 of 768) ----
    slice_gemm<24, 16, 16, NJ>(Wqkv + (size_t)l * 196608, 768, w * 96, &sh[0][0], 256,
                               arena);
    __syncthreads();
    slice_reduce<24, 16, NJ>(arena, [&](int cc, int j, float s) {
      int col = w * 96 + cc;
      int row = PRE ? (rbase + j) : (8 + ti);
      int slot = PRE ? (b * 5) : (b * 5 + j);
      if (col < 256)
        shq[b * 1280 + j * 256 + col] = s;
      else if (col < 512)
        Kc[((size_t)(l * 40 + slot) * 40 + row) * 256 + col - 256] = s;
      else
        Vc[((size_t)(l * 40 + slot) * 40 + row) * 256 + col - 512] = s;
    });
    gbar(bar, ++eb);
    // ---- attention: WG w = head w ----
    {
      for (int i = t; i < NJ * 40; i += 512) ips[i / 40][i % 40] = shptr[b * 200 + i];
      float* sq = arena;        // [NJ][32]
      float* sc = arena + 160;  // [NJ][40]
      for (int i = t; i < NJ * 32; i += 512)
        sq[i] = shq[b * 1280 + (i >> 5) * 256 + w * 32 + (i & 31)];
      __syncthreads();
      for (int i = t; i < NJ * 40; i += 512) {
        int j = i / 40, jj = i % 40;
        int rowj = PRE ? (rbase + j) : (8 + ti);
        if (jj <= rowj) {
          const float* kp = Kc + ((size_t)(l * 40 + ips[j][jj]) * 40 + jj) * 256 + w * 32;
          float s = 0.f;
#pragma unroll
          for (int d = 0; d < 32; d += 4) {
            float4 k4 = *(const float4*)(kp + d);
            s = fmaf(sq[j * 32 + d], k4.x,
                     fmaf(sq[j * 32 + d + 1], k4.y,
                          fmaf(sq[j * 32 + d + 2], k4.z,
                               fmaf(sq[j * 32 + d + 3], k4.w, s))));
          }
          sc[j * 40 + jj] = s * 0.17677669529663687f;  // 1/sqrt(32)
        }
      }
      __syncthreads();
      if (t < NJ) {
        int rowj = PRE ? (rbase + t) : (8 + ti);
        float m = -3.4e38f;
        for (int jj = 0; jj <= rowj; ++jj) m = fmaxf(m, sc[t * 40 + jj]);
        float su = 0.f;
        for (int jj = 0; jj <= rowj; ++jj) su += expf(sc[t * 40 + jj] - m);
        for (int jj = 0; jj <= rowj; ++jj) sc[t * 40 + jj] = expf(sc[t * 40 + jj] - m) / su;
      }
      __syncthreads();
      // PV: write attn-out over own q slice in shq
      for (int i = t; i < NJ * 32; i += 512) {
        int j = i >> 5, d = i & 31;
        int rowj = PRE ? (rbase + j) : (8 + ti);
        float o = 0.f;
        for (int jj = 0; jj <= rowj; ++jj)
          o = fmaf(sc[j * 40 + jj],
                   Vc[((size_t)(l * 40 + ips[j][jj]) * 40 + jj) * 256 + w * 32 + d], o);
        shq[b * 1280 + j * 256 + w * 32 + d] = o;
      }
    }
    gbar(bar, ++eb);
    // ---- Wo slice (cols w*32) + residual -> shxn ----
    for (int i = t; i < NJ * 256; i += 512) sh[i >> 8][i & 255] = shq[b * 1280 + i];
    __syncthreads();
    slice_gemm<8, 32, 8, NJ>(Wo + (size_t)l * 65536, 256, w * 32, &sh[0][0], 256, arena);
    __syncthreads();
    slice_reduce<8, 32, NJ>(arena, [&](int cc, int j, float s) {
      int col = w * 32 + cc;
      shxn[b * 1280 + j * 256 + col] = sx[j][col] + s;
    });
    gbar(bar, ++eb);
    // ---- refresh x, LN2, FF1 slice (cols w*128) ----
    for (int i = t; i < NJ * 256; i += 512) sx[i >> 8][i & 255] = shxn[b * 1280 + i];
    __syncthreads();
    ln_rows(sx, sh, ln2s + l * 256, ln2b + l * 256, NJ);
    __syncthreads();
    slice_gemm<32, 16, 16, NJ>(Wff1 + (size_t)l * 262144, 1024, w * 128, &sh[0][0], 256,
                               arena);
    __syncthreads();
    slice_reduce<32, 16, NJ>(arena, [&](int cc, int j, float s) {
      int col = w * 128 + cc;
      shf1[b * 5120 + j * 1024 + col] = fmaxf(s + bff1[l * 1024 + col], 0.f);
    });
    gbar(bar, ++eb);
    // ---- FF2 slice (cols w*32, k=1024) + residual -> shxf ----
    for (int i = t; i < NJ * 256; i += 512)
      *(float4*)&arena[i * 4] = *(const float4*)&shf1[b * 5120 + i * 4];
    __syncthreads();
    slice_gemm<8, 32, 32, NJ>(Wff2 + (size_t)l * 262144, 256, w * 32, arena, 1024,
                              arena + 5120);
    __syncthreads();
    slice_reduce<8, 32, NJ>(arena + 5120, [&](int cc, int j, float s) {
      int col = w * 32 + cc;
      shxf[b * 1280 + j * 256 + col] = sx[j][col] + s + bff2[l * 256 + col];
    });
    gbar(bar, ++eb);
    for (int i = t; i < NJ * 256; i += 512) sx[i >> 8][i & 255] = shxf[b * 1280 + i];
    __syncthreads();
  }
}

// ---------------- head ----------------
template <int NJ>
__device__ void run_head(int b, int w, const float* __restrict__ hW1,
                         const float* __restrict__ hb1, const float* __restrict__ hW2,
                         const float* __restrict__ hb2, float (*sx)[256],
                         float (*sh)[256], float* arena, float* __restrict__ shq,
                         float* __restrict__ shlg, int* bar, int& eb) {
  const int t = threadIdx.x;
  slice_gemm<8, 32, 8, NJ>(hW1, 256, w * 32, &sx[0][0], 256, arena);
  __syncthreads();
  slice_reduce<8, 32, NJ>(arena, [&](int cc, int j, float s) {
    int col = w * 32 + cc;
    shq[b * 1280 + j * 256 + col] = fmaxf(s + hb1[col], 0.f);
  });
  gbar(bar, ++eb);
  for (int i = t; i < NJ * 256; i += 512) sh[i >> 8][i & 255] = shq[b * 1280 + i];
  __syncthreads();
  slice_gemm<2, 32, 8, NJ>(hW2, 64, w * 8, &sh[0][0], 256, arena);
  __syncthreads();
  slice_reduce<2, 32, NJ>(arena, [&](int cc, int j, float s) {
    int col = w * 8 + cc;
    shlg[b * 320 + j * 64 + col] = s + hb2[col];
  });
  gbar(bar, ++eb);
}

// ---------------- persistent decode kernel ----------------
__global__ __launch_bounds__(512, 1) void k_dec(
    const float* __restrict__ codes, const float* __restrict__ tok_emb,
    const float* __restrict__ pos_emb, const float* __restrict__ Wqkv,
    const float* __restrict__ Wo, const float* __restrict__ ln1s,
    const float* __restrict__ ln1b, const float* __restrict__ ln2s,
    const float* __restrict__ ln2b, const float* __restrict__ Wff1,
    const float* __restrict__ bff1, const float* __restrict__ Wff2,
    const float* __restrict__ bff2, const float* __restrict__ hW1,
    const float* __restrict__ hb1, const float* __restrict__ hW2,
    const float* __restrict__ hb2, float* __restrict__ Kc, float* __restrict__ Vc,
    float* __restrict__ shq, float* __restrict__ shxn, float* __restrict__ shxf,
    float* __restrict__ shf1, float* __restrict__ shlg, int* __restrict__ shseq,
    int* __restrict__ shptr, int* __restrict__ bars, float* __restrict__ out) {
  const int t = threadIdx.x;
  const int b = blockIdx.x >> 3;
  const int w = blockIdx.x & 7;
  int* bar = bars + b * 32;
  int eb = 0;

  __shared__ __align__(16) float sx[5][256];
  __shared__ __align__(16) float sh[5][256];
  __shared__ __align__(16) float arena[10240];
  __shared__ int ips[5][40];
  __shared__ int sSeq[5][32];
  __shared__ int sPtr[5][40];
  __shared__ float sLls[5];

  // ---- init shared state (WG0 of each group) ----
  if (w == 0) {
    for (int i = t; i < 160; i += 512) {
      int v = ((i & 31) == 0) ? 1 : 0;
      sSeq[i >> 5][i & 31] = v;
      shseq[b * 160 + i] = v;
    }
    for (int i = t; i < 200; i += 512) {
      sPtr[i / 40][i % 40] = b * 5;
      shptr[b * 200 + i] = b * 5;
    }
    if (t < 5) sLls[t] = (t == 0) ? 0.f : -100000.0f;
  }
  gbar(bar, ++eb);

  for (int ti = 0; ti < 31; ++ti) {
    const bool pre = (ti == 0);
    if (pre) {
      run_chunk<1, 5>(b, w, ti, 0, codes, tok_emb, pos_emb, Wqkv, Wo, ln1s, ln1b, ln2s,
                      ln2b, Wff1, bff1, Wff2, bff2, Kc, Vc, shq, shxn, shxf, shf1,
                      shseq, shptr, sx, sh, arena, ips, bar, eb);
      run_chunk<1, 4>(b, w, ti, 5, codes, tok_emb, pos_emb, Wqkv, Wo, ln1s, ln1b, ln2s,
                      ln2b, Wff1, bff1, Wff2, bff2, Kc, Vc, shq, shxn, shxf, shf1,
                      shseq, shptr, sx, sh, arena, ips, bar, eb);
      run_head<4>(b, w, hW1, hb1, hW2, hb2, sx, sh, arena, shq, shlg, bar, eb);
    } else {
      run_chunk<0, 5>(b, w, ti, 0, codes, tok_emb, pos_emb, Wqkv, Wo, ln1s, ln1b, ln2s,
                      ln2b, Wff1, bff1, Wff2, bff2, Kc, Vc, shq, shxn, shxf, shf1,
                      shseq, shptr, sx, sh, arena, ips, bar, eb);
      run_head<5>(b, w, hW1, hb1, hW2, hb2, sx, sh, arena, shq, shlg, bar, eb);
    }
    // ---- beam update (group WG0, exact tie semantics) ----
    if (w == 0) {
      float* lgl = arena;          // [5][64]
      float* bdist = arena + 320;  // [5][64]
      float* bd = arena + 640;     // 25
      float* nll = arena + 672;    // 5
      float* rm = arena + 688;     // 5
      float* rs = arena + 696;     // 5
      int* bc = (int*)(arena + 704);    // 25
      int* nts = (int*)(arena + 736);   // 5
      int* oldx = (int*)(arena + 744);  // 5
      int* osq = (int*)(arena + 752);   // 160
      int* opt = (int*)(arena + 912);   // 200
      for (int i = t; i < 320; i += 512) {
        int r = i >> 6, c = i & 63;
        lgl[i] = shlg[b * 320 + (pre ? 3 : r) * 64 + c];
      }
      for (int i = t; i < 160; i += 512) osq[i] = sSeq[i >> 5][i & 31];
      for (int i = t; i < 200; i += 512) opt[i] = sPtr[i / 40][i % 40];
      __syncthreads();
      if (t < 5) {
        float m = -3.4e38f;
        for (int j = 0; j < 64; ++j) m = fmaxf(m, lgl[t * 64 + j]);
        float s = 0.f;
        for (int j = 0; j < 64; ++j) s += expf(lgl[t * 64 + j] - m);
        rm[t] = m;
        rs[t] = s;
      }
      __syncthreads();
      for (int i = t; i < 320; i += 512) {
        int r = i >> 6;
        bdist[i] = logf(expf(lgl[i] - rm[r]) / rs[r] + 1e-8f);
      }
      __syncthreads();
      if (t < 5) {
        float pv = 3.4e38f;
        int pi = -1;
        for (int r = 0; r < 5; ++r) {
          float bv = -3.4e38f;
          int bi = -1;
          for (int j = 0; j < 64; ++j) {
            float v = bdist[t * 64 + j];
            bool lessprev = (v < pv) || (v == pv && j > pi);
            if (lessprev && v > bv) { bv = v; bi = j; }
          }
          bd[t * 5 + r] = bv;
          bc[t * 5 + r] = bi;
          pv = bv;
          pi = bi;
        }
      }
      __syncthreads();
      if (t == 0) {
        float pv = 3.4e38f;
        int pi = -1;
        for (int r = 0; r < 5; ++r) {
          float bv = -3.4e38f;
          int bi = -1;
          for (int idx = 0; idx < 25; ++idx) {
            int kb = idx / 5, jj = idx % 5;
            float v = bd[kb * 5 + jj] + sLls[kb];
            bool lessprev = (v < pv) || (v == pv && idx > pi);
            if (lessprev && v > bv) { bv = v; bi = idx; }
          }
          int kb = bi / 5, jj = bi % 5;
          int tok = bc[kb * 5 + jj];
          nts[r] = tok;
          oldx[r] = kb;
          nll[r] = (tok == 2) ? (bv - 100000.0f) : bv;
          pv = bv;
          pi = bi;
        }
      }
      __syncthreads();
      for (int i = t; i < 160; i += 512) {
        int bm = i >> 5, j2 = i & 31;
        int v = osq[oldx[bm] * 32 + j2];
        if (j2 == ti + 1) v = nts[bm];
        sSeq[bm][j2] = v;
        shseq[b * 160 + i] = v;
      }
      int r1 = 8 + ti;
      for (int i = t; i < 200; i += 512) {
        int bm = i / 40, j2 = i % 40;
        int v = (j2 <= r1) ? opt[oldx[bm] * 40 + j2] : (b * 5 + bm);
        sPtr[bm][j2] = v;
        shptr[b * 200 + i] = v;
      }
      if (t < 5) sLls[t] = nll[t];
    }
    gbar(bar, ++eb);
  }
  // ---- output: bseqs (40,32) as float, then blls (40,) ----
  if (w == 0) {
    for (int i = t; i < 160; i += 512) out[b * 160 + i] = (float)sSeq[i >> 5][i & 31];
    if (t < 5) out[1280 + b * 5 + t] = sLls[t];
  }
}

// ---------------- host ----------------
extern "C" void kernel_launch(void* const* d_in, const int* in_sizes, int n_in,
                              void* d_out, int out_size, void* d_ws, size_t ws_size,
                              hipStream_t stream) {
  const float* voxels = (const float*)d_in[0];
  const float* ck1 = (const float*)d_in[1];
  const float* cb1 = (const float*)d_in[2];
  const float* ck2 = (const float*)d_in[3];
  const float* cb2 = (const float*)d_in[4];
  const float* ck3 = (const float*)d_in[5];
  const float* cb3 = (const float*)d_in[6];
  const float* ck4 = (const float*)d_in[7];
  const float* cb4 = (const float*)d_in[8];
  const float* ck5 = (const float*)d_in[9];
  const float* cb5 = (const float*)d_in[10];
  const float* tok_emb = (const float*)d_in[11];
  const float* pos_emb = (const float*)d_in[12];
  const float* Wqkv = (const float*)d_in[13];
  const float* Wo = (const float*)d_in[14];
  const float* ln1s = (const float*)d_in[15];
  const float* ln1b = (const float*)d_in[16];
  const float* ln2s = (const float*)d_in[17];
  const float* ln2b = (const float*)d_in[18];
  const float* Wff1 = (const float*)d_in[19];
  const float* bff1 = (const float*)d_in[20];
  const float* Wff2 = (const float*)d_in[21];
  const float* bff2 = (const float*)d_in[22];
  const float* hW1 = (const float*)d_in[23];
  const float* hb1 = (const float*)d_in[24];
  const float* hW2 = (const float*)d_in[25];
  const float* hb2 = (const float*)d_in[26];

  float* ws = (float*)d_ws;
  // conv chain buffers
  float* c1 = ws;              // 8,388,608 f
  float* c2 = c1 + 8388608;    // 2,097,152 f
  float* c3 = c2 + 2097152;    //   524,288 f
  float* c4 = c3 + 524288;     //   131,072 f
  float* codes = c4 + 131072;  //    16,384 f
  // decode region aliases c1 (dead after conv_t2); all cross-WG traffic is
  // barrier-fenced, so stale lines are invalidated before any read.
  float* Kc = ws;                    // [4][40][40][256] = 1,638,400 f
  float* Vc = Kc + 1638400;          // 1,638,400 f
  float* shq = Vc + 1638400;         // [8][5][256]  = 10,240 f
  float* shxn = shq + 10240;         // 10,240 f
  float* shxf = shxn + 10240;        // 10,240 f
  float* shf1 = shxf + 10240;        // [8][5][1024] = 40,960 f
  float* shlg = shf1 + 40960;        // [8][5][64]   = 2,560 f
  int* shseq = (int*)(shlg + 2560);  // [8][5][32]   = 1,280 i
  int* shptr = shseq + 1280;         // [8][5][40]   = 1,600 i
  int* bars = shptr + 1600;          // [8][32]      = 256 i

  conv_v1<1, 32, 32, 128><<<8 * 32 * 128, 256, 0, stream>>>(voxels, ck1, cb1, c1);
  conv_t2<<<8 * 16 * 8, 256, 0, stream>>>(c1, ck2, cb2, c2);
  conv_t3<<<8 * 2 * 32, 256, 0, stream>>>(c2, ck3, cb3, c3);
  conv_v2<<<8 * 256, 64, 0, stream>>>(c3, ck4, cb4, c4);
  conv_v3<<<8 * 8, 256, 0, stream>>>(c4, ck5, cb5, codes);

  hipMemsetAsync(bars, 0, 256 * sizeof(int), stream);
  k_dec<<<64, 512, 0, stream>>>(codes, tok_emb, pos_emb, Wqkv, Wo, ln1s, ln1b, ln2s,
                                ln2b, Wff1, bff1, Wff2, bff2, hW1, hb1, hW2, hb2, Kc,
                                Vc, shq, shxn, shxf, shf1, shlg, shseq, shptr, bars,
                                (float*)d_out);
}